// Round 5
// baseline (652.463 us; speedup 1.0000x reference)
//
#include <hip/hip_runtime.h>
#include <hip/hip_bf16.h>
#include <math.h>

// Problem constants (Qwen3-style attention block)
#define B_   2
#define S_   2048
#define D_   2048
#define H_   16
#define HK_  8
#define HD_  128
#define BS_  (B_ * S_)          // 4096 rows
#define NQKV 4096               // combined q(2048) + k(1024) + v(1024) cols
#define SCALE 0.08838834764831845f  // 1/sqrt(128)

typedef __bf16 bf16x8 __attribute__((ext_vector_type(8)));
typedef __bf16 bf16x4 __attribute__((ext_vector_type(4)));
typedef float  f32x4  __attribute__((ext_vector_type(4)));

#define AS1(p) ((const __attribute__((address_space(1))) void*)(p))
#define AS3(p) ((__attribute__((address_space(3))) void*)(p))

// ---------------------------------------------------------------------------
// fp32 -> bf16 convert
// ---------------------------------------------------------------------------
__global__ __launch_bounds__(256) void cvt_bf16(const float* __restrict__ in,
                                                __bf16* __restrict__ out, int n4) {
    int i = blockIdx.x * 256 + threadIdx.x;
    if (i < n4) {
        float4 v = reinterpret_cast<const float4*>(in)[i];
        bf16x4 o = {(__bf16)v.x, (__bf16)v.y, (__bf16)v.z, (__bf16)v.w};
        reinterpret_cast<bf16x4*>(out)[i] = o;
    }
}

// ---------------------------------------------------------------------------
// bf16 MFMA NT GEMM (m97 structure): C[M,N] = A[M,K] * W[N,K]^T
// ---------------------------------------------------------------------------
template <typename CT>
__global__ __launch_bounds__(256) void gemm_bf16_nt(const __bf16* __restrict__ A,
                                                    const __bf16* __restrict__ W,
                                                    CT* __restrict__ C,
                                                    int M, int N, int K) {
    __shared__ __bf16 As[128 * 32];
    __shared__ __bf16 Bs[128 * 32];

    const int t    = threadIdx.x;
    const int w    = t >> 6;
    const int lane = t & 63;
    const int col  = lane & 15;
    const int quad = lane >> 4;
    const int wm   = w >> 1;
    const int wn   = w & 1;

    const int m0 = blockIdx.y * 128;
    const int n0 = blockIdx.x * 128;

    const int lrow = lane >> 2;
    const int lk   = (lane & 3) * 8;

    const __bf16* agp = A + (size_t)(m0 + w * 32 + lrow) * K + lk;
    const __bf16* wgp = W + (size_t)(n0 + w * 32 + lrow) * K + lk;
    __bf16* alp = As + (w * 32) * 32;
    __bf16* blp = Bs + (w * 32) * 32;

    f32x4 acc[4][4];
    #pragma unroll
    for (int m = 0; m < 4; m++)
        #pragma unroll
        for (int n = 0; n < 4; n++) acc[m][n] = (f32x4){0.f, 0.f, 0.f, 0.f};

    #pragma unroll 1
    for (int k0 = 0; k0 < K; k0 += 32) {
        __builtin_amdgcn_global_load_lds(AS1(agp + k0),                  AS3(alp),           16, 0, 0);
        __builtin_amdgcn_global_load_lds(AS1(agp + k0 + (size_t)16 * K), AS3(alp + 16 * 32), 16, 0, 0);
        __builtin_amdgcn_global_load_lds(AS1(wgp + k0),                  AS3(blp),           16, 0, 0);
        __builtin_amdgcn_global_load_lds(AS1(wgp + k0 + (size_t)16 * K), AS3(blp + 16 * 32), 16, 0, 0);
        __syncthreads();

        bf16x8 af[4], bfr[4];
        #pragma unroll
        for (int m = 0; m < 4; m++)
            af[m] = *reinterpret_cast<const bf16x8*>(&As[(wm * 64 + m * 16 + col) * 32 + quad * 8]);
        #pragma unroll
        for (int n = 0; n < 4; n++)
            bfr[n] = *reinterpret_cast<const bf16x8*>(&Bs[(wn * 64 + n * 16 + col) * 32 + quad * 8]);

        #pragma unroll
        for (int m = 0; m < 4; m++)
            #pragma unroll
            for (int n = 0; n < 4; n++)
                acc[m][n] = __builtin_amdgcn_mfma_f32_16x16x32_bf16(af[m], bfr[n], acc[m][n], 0, 0, 0);
        __syncthreads();
    }

    #pragma unroll
    for (int m = 0; m < 4; m++) {
        #pragma unroll
        for (int r = 0; r < 4; r++) {
            size_t row = m0 + wm * 64 + m * 16 + quad * 4 + r;
            CT* cp = C + row * N + n0 + wn * 64 + col;
            #pragma unroll
            for (int n = 0; n < 4; n++) cp[n * 16] = (CT)acc[m][n][r];
        }
    }
}

// ---------------------------------------------------------------------------
// Fused per-head RMSNorm + RoPE, in-place on bf16 qkv buffer.
// ---------------------------------------------------------------------------
__global__ __launch_bounds__(128) void norm_rope(__bf16* __restrict__ base,
                                                 const float* __restrict__ w) {
    __shared__ float sred[2];
    __shared__ float nv[128];

    const int row  = blockIdx.x;
    const int s    = row & (S_ - 1);
    const int head = blockIdx.y;
    const int d    = threadIdx.x;

    __bf16* p = base + (size_t)row * NQKV + (size_t)head * HD_;
    float x = (float)p[d];

    float ss = x * x;
    #pragma unroll
    for (int off = 32; off; off >>= 1) ss += __shfl_xor(ss, off);
    if ((threadIdx.x & 63) == 0) sred[threadIdx.x >> 6] = ss;
    __syncthreads();
    float mean = (sred[0] + sred[1]) * (1.0f / 128.0f);
    float rs = rsqrtf(mean + 1e-6f);

    float n = x * rs * w[d];
    nv[d] = n;
    __syncthreads();

    const int i = d & 63;
    float inv_freq = expf(-13.815510557964274f * (float)(2 * i) * (1.0f / 128.0f));
    float ang = (float)s * inv_freq;
    float sn, cs;
    sincosf(ang, &sn, &cs);

    float other = nv[d ^ 64];
    float r = (d < 64) ? (n * cs - other * sn)
                       : (other * sn + n * cs);
    p[d] = (__bf16)r;
}

// ---------------------------------------------------------------------------
// V transpose: vt[(b*HK+kvh)*128 + dim][s] = v[b*S+s][kvh*128+dim]
// ---------------------------------------------------------------------------
__global__ __launch_bounds__(256) void transpose_v(const __bf16* __restrict__ qkv,
                                                   __bf16* __restrict__ vt) {
    __shared__ __bf16 Ls[64][136];
    const int t  = threadIdx.x;
    const int bk = blockIdx.y;            // b*8 + kvh
    const int b  = bk >> 3;
    const int kvh = bk & 7;
    const int s0 = blockIdx.x * 64;

    #pragma unroll
    for (int i = 0; i < 4; i++) {
        int f = t + i * 256;
        int row = f >> 4;
        int d8 = (f & 15) * 8;
        bf16x8 v = *reinterpret_cast<const bf16x8*>(
            &qkv[(size_t)(b * S_ + s0 + row) * NQKV + 3072 + kvh * HD_ + d8]);
        *reinterpret_cast<bf16x8*>(&Ls[row][d8]) = v;
    }
    __syncthreads();

    #pragma unroll
    for (int i = 0; i < 4; i++) {
        int f = t + i * 256;
        int dim = f >> 3;
        int kc = f & 7;
        bf16x8 o;
        #pragma unroll
        for (int e = 0; e < 8; e++) o[e] = Ls[kc * 8 + e][dim];
        *reinterpret_cast<bf16x8*>(
            &vt[((size_t)bk * HD_ + dim) * S_ + s0 + kc * 8]) = o;
    }
}

// ---------------------------------------------------------------------------
// MFMA bf16 flash attention (causal, GQA rep=2), load-balanced pairing.
// Grid: (16 pairs, B*H). Block: 256 threads = 4 waves.
// Block p handles q-subtiles qtA=p (64 rows) and qtB=31-p (64 rows) of one
// (b,h): every block does exactly (qtA+1)+(qtB+1) = 33 subtile-units.
// Wave w owns rows [w*16, w*16+16) of EACH subtile. K/V fragments are read
// once per KV tile and shared across both active subtiles.
// LDS: union{ Qs[128][136] | Ks[64][136]+Vt[128][72] } = 35840 B
//      + Ps[4][32][72] = 18432 B  -> 54272 B total, 2 blocks/CU.
// ---------------------------------------------------------------------------
__global__ __launch_bounds__(256) void attn_mfma(const __bf16* __restrict__ qkv,
                                                 const __bf16* __restrict__ vt,
                                                 __bf16* __restrict__ ao) {
    __shared__ __align__(16) char smem[35840];
    __bf16 (*Qs)[136] = reinterpret_cast<__bf16(*)[136]>(smem);
    __bf16 (*Ks)[136] = reinterpret_cast<__bf16(*)[136]>(smem);
    __bf16 (*Vt)[72]  = reinterpret_cast<__bf16(*)[72]>(smem + 17408);
    __shared__ __bf16 Ps[4][32][72];

    const int t    = threadIdx.x;
    const int w    = t >> 6;
    const int lane = t & 63;
    const int col  = lane & 15;
    const int quad = lane >> 4;

    const int bh  = blockIdx.y;
    const int b   = bh >> 4;
    const int h   = bh & 15;
    const int kvh = h >> 1;

    const int p   = blockIdx.x;       // pair index 0..15
    const int qtA = p;                // early subtile
    const int qtB = 31 - p;           // late subtile
    const int r0A = qtA * 64;
    const int r0B = qtB * 64;

    const __bf16* vbase = vt + ((size_t)(b * HK_ + kvh) * HD_) * S_;

    // ---- stage both Q subtiles (rows 0..63 = A, 64..127 = B) ----
    #pragma unroll
    for (int i = 0; i < 8; i++) {
        int f   = t + i * 256;
        int row = f >> 4;
        int d8  = (f & 15) * 8;
        int grow = (row < 64) ? (r0A + row) : (r0B + row - 64);
        bf16x8 v = *reinterpret_cast<const bf16x8*>(
            &qkv[(size_t)(b * S_ + grow) * NQKV + h * HD_ + d8]);
        *reinterpret_cast<bf16x8*>(&Qs[row][d8]) = v;
    }
    __syncthreads();

    bf16x8 qf[2][4];
    #pragma unroll
    for (int tl = 0; tl < 2; tl++) {
        const int m = tl * 64 + w * 16 + col;
        #pragma unroll
        for (int k = 0; k < 4; k++)
            qf[tl][k] = *reinterpret_cast<const bf16x8*>(&Qs[m][k * 32 + quad * 8]);
    }

    f32x4 oA[8], oB[8];
    #pragma unroll
    for (int i = 0; i < 8; i++) { oA[i] = (f32x4){0.f,0.f,0.f,0.f}; oB[i] = (f32x4){0.f,0.f,0.f,0.f}; }
    float mA[4], lA[4], mB[4], lB[4];
    #pragma unroll
    for (int r = 0; r < 4; r++) { mA[r] = -INFINITY; lA[r] = 0.f; mB[r] = -INFINITY; lB[r] = 0.f; }

    // online-softmax + P write for one 16x64 score block
    auto softmax_tile = [&](f32x4* s, float* m_r, float* l_r, f32x4* o,
                            int kofs, int psrow) {
        float alpha[4];
        #pragma unroll
        for (int r = 0; r < 4; r++) {
            float v0 = s[0][r] * SCALE, v1 = s[1][r] * SCALE;
            float v2 = s[2][r] * SCALE, v3 = s[3][r] * SCALE;
            if (kofs >= 0) {
                int qloc = w * 16 + quad * 4 + r;
                if (kofs + 0 * 16 + col > qloc) v0 = -INFINITY;
                if (kofs + 1 * 16 + col > qloc) v1 = -INFINITY;
                if (kofs + 2 * 16 + col > qloc) v2 = -INFINITY;
                if (kofs + 3 * 16 + col > qloc) v3 = -INFINITY;
            }
            float mx = fmaxf(fmaxf(v0, v1), fmaxf(v2, v3));
            #pragma unroll
            for (int off = 8; off; off >>= 1) mx = fmaxf(mx, __shfl_xor(mx, off));
            float mn = fmaxf(m_r[r], mx);
            float al = __expf(m_r[r] - mn);
            float p0 = __expf(v0 - mn);
            float p1 = __expf(v1 - mn);
            float p2 = __expf(v2 - mn);
            float p3 = __expf(v3 - mn);
            float ts = p0 + p1 + p2 + p3;
            #pragma unroll
            for (int off = 8; off; off >>= 1) ts += __shfl_xor(ts, off);
            l_r[r] = l_r[r] * al + ts;
            m_r[r] = mn;
            alpha[r] = al;
            Ps[w][psrow + quad * 4 + r][0 * 16 + col] = (__bf16)p0;
            Ps[w][psrow + quad * 4 + r][1 * 16 + col] = (__bf16)p1;
            Ps[w][psrow + quad * 4 + r][2 * 16 + col] = (__bf16)p2;
            Ps[w][psrow + quad * 4 + r][3 * 16 + col] = (__bf16)p3;
        }
        #pragma unroll
        for (int n = 0; n < 8; n++)
            #pragma unroll
            for (int r = 0; r < 4; r++)
                o[n][r] *= alpha[r];
    };

    const int ntiles = qtB + 1;
    for (int ti = 0; ti < ntiles; ti++) {
        const int t0 = ti * 64;
        __syncthreads();   // prior tile's LDS reads (and iter-0 qf grab) done

        // ---- stage K tile (64 keys x 128 dims) ----
        #pragma unroll
        for (int i = 0; i < 4; i++) {
            int f   = t + i * 256;
            int row = f >> 4;
            int d8  = (f & 15) * 8;
            bf16x8 kv = *reinterpret_cast<const bf16x8*>(
                &qkv[(size_t)(b * S_ + t0 + row) * NQKV + 2048 + kvh * HD_ + d8]);
            *reinterpret_cast<bf16x8*>(&Ks[row][d8]) = kv;
        }
        // ---- stage V^T tile (128 dims x 64 keys) ----
        #pragma unroll
        for (int i = 0; i < 4; i++) {
            int f   = t + i * 256;
            int dim = f >> 3;
            int kc  = f & 7;
            bf16x8 vv = *reinterpret_cast<const bf16x8*>(
                &vbase[(size_t)dim * S_ + t0 + kc * 8]);
            *reinterpret_cast<bf16x8*>(&Vt[dim][kc * 8]) = vv;
        }
        __syncthreads();

        const bool actA = (ti <= qtA);   // uniform across block

        // ---- S = Q K^T, K-fragments shared across both subtiles ----
        f32x4 sA[4], sB[4];
        #pragma unroll
        for (int n = 0; n < 4; n++) { sA[n] = (f32x4){0.f,0.f,0.f,0.f}; sB[n] = (f32x4){0.f,0.f,0.f,0.f}; }
        #pragma unroll
        for (int n = 0; n < 4; n++) {
            #pragma unroll
            for (int k = 0; k < 4; k++) {
                bf16x8 bf = *reinterpret_cast<const bf16x8*>(
                    &Ks[n * 16 + col][k * 32 + quad * 8]);
                if (actA) sA[n] = __builtin_amdgcn_mfma_f32_16x16x32_bf16(qf[0][k], bf, sA[n], 0, 0, 0);
                sB[n] = __builtin_amdgcn_mfma_f32_16x16x32_bf16(qf[1][k], bf, sB[n], 0, 0, 0);
            }
        }

        // ---- softmax for active subtiles ----
        if (actA) softmax_tile(sA, mA, lA, oA, t0 - r0A, 0);
        softmax_tile(sB, mB, lB, oB, t0 - r0B, 16);

        // ---- PV, V-fragments shared ----
        bf16x8 pfA[2], pfB[2];
        #pragma unroll
        for (int ks = 0; ks < 2; ks++) {
            if (actA) pfA[ks] = *reinterpret_cast<const bf16x8*>(&Ps[w][col][ks * 32 + quad * 8]);
            pfB[ks] = *reinterpret_cast<const bf16x8*>(&Ps[w][16 + col][ks * 32 + quad * 8]);
        }
        #pragma unroll
        for (int n = 0; n < 8; n++) {
            #pragma unroll
            for (int ks = 0; ks < 2; ks++) {
                bf16x8 vf = *reinterpret_cast<const bf16x8*>(
                    &Vt[n * 16 + col][ks * 32 + quad * 8]);
                if (actA) oA[n] = __builtin_amdgcn_mfma_f32_16x16x32_bf16(pfA[ks], vf, oA[n], 0, 0, 0);
                oB[n] = __builtin_amdgcn_mfma_f32_16x16x32_bf16(pfB[ks], vf, oB[n], 0, 0, 0);
            }
        }
    }

    // ---- epilogue: both subtiles ----
    #pragma unroll
    for (int r = 0; r < 4; r++) {
        float invA = 1.0f / lA[r];
        float invB = 1.0f / lB[r];
        int qrowA = r0A + w * 16 + quad * 4 + r;
        int qrowB = r0B + w * 16 + quad * 4 + r;
        __bf16* opA = ao + (size_t)(b * S_ + qrowA) * (H_ * HD_) + h * HD_ + col;
        __bf16* opB = ao + (size_t)(b * S_ + qrowB) * (H_ * HD_) + h * HD_ + col;
        #pragma unroll
        for (int n = 0; n < 8; n++) {
            opA[n * 16] = (__bf16)(oA[n][r] * invA);
            opB[n * 16] = (__bf16)(oB[n][r] * invB);
        }
    }
}

// ---------------------------------------------------------------------------
extern "C" void kernel_launch(void* const* d_in, const int* in_sizes, int n_in,
                              void* d_out, int out_size, void* d_ws, size_t ws_size,
                              hipStream_t stream) {
    const float* x  = (const float*)d_in[0];
    const float* wq = (const float*)d_in[1];
    const float* wk = (const float*)d_in[2];
    const float* wv = (const float*)d_in[3];
    const float* wo = (const float*)d_in[4];
    const float* qw = (const float*)d_in[5];
    const float* kw = (const float*)d_in[6];
    float* out = (float*)d_out;

    // workspace (bf16 elements), total 50.33M elems = 100.66 MB
    __bf16* ws  = (__bf16*)d_ws;
    __bf16* xb  = ws;                               // [4096][2048]  8.4M
    __bf16* wb  = xb  + (size_t)8388608;            // [4096][2048]  8.4M (wq|wk|wv)
    __bf16* wob = wb  + (size_t)8388608;            // [2048][2048]  4.2M
    __bf16* qkv = wob + (size_t)4194304;            // [4096][4096] 16.8M
    __bf16* ao  = qkv + (size_t)16777216;           // [4096][2048]  8.4M
    __bf16* vtg = ao  + (size_t)8388608;            // [16][128][2048] 4.2M

    cvt_bf16<<<2097152 / 256, 256, 0, stream>>>(x,  xb,  2097152);
    cvt_bf16<<<1048576 / 256, 256, 0, stream>>>(wq, wb,  1048576);
    cvt_bf16<<< 524288 / 256, 256, 0, stream>>>(wk, wb + (size_t)2048 * 2048, 524288);
    cvt_bf16<<< 524288 / 256, 256, 0, stream>>>(wv, wb + (size_t)3072 * 2048, 524288);
    cvt_bf16<<<1048576 / 256, 256, 0, stream>>>(wo, wob, 1048576);

    // fused QKV projection
    gemm_bf16_nt<__bf16><<<dim3(NQKV / 128, BS_ / 128), 256, 0, stream>>>(
        xb, wb, qkv, BS_, NQKV, D_);

    // RMSNorm + RoPE on q and k
    norm_rope<<<dim3(BS_, H_),  128, 0, stream>>>(qkv,        qw);
    norm_rope<<<dim3(BS_, HK_), 128, 0, stream>>>(qkv + 2048, kw);

    // global V^T
    transpose_v<<<dim3(S_ / 64, B_ * HK_), 256, 0, stream>>>(qkv, vtg);

    // causal GQA attention (load-balanced pairs)
    attn_mfma<<<dim3(16, B_ * H_), 256, 0, stream>>>(qkv, vtg, ao);

    // output projection
    gemm_bf16_nt<float><<<dim3(D_ / 128, BS_ / 128), 256, 0, stream>>>(
        ao, wob, out, BS_, D_, H_ * HD_);
}

// Round 6
// 420.220 us; speedup vs baseline: 1.5527x; 1.5527x over previous
//
#include <hip/hip_runtime.h>
#include <hip/hip_bf16.h>
#include <math.h>

// Problem constants (Qwen3-style attention block)
#define B_   2
#define S_   2048
#define D_   2048
#define H_   16
#define HK_  8
#define HD_  128
#define BS_  (B_ * S_)          // 4096 rows
#define NQKV 4096               // combined q(2048) + k(1024) + v(1024) cols
#define SCALE 0.08838834764831845f  // 1/sqrt(128)

typedef __bf16 bf16x8 __attribute__((ext_vector_type(8)));
typedef __bf16 bf16x4 __attribute__((ext_vector_type(4)));
typedef float  f32x4  __attribute__((ext_vector_type(4)));

#define AS1(p) ((const __attribute__((address_space(1))) void*)(p))
#define AS3(p) ((__attribute__((address_space(3))) void*)(p))

// 16-lane (DPP row) rotate-reduce: VALU latency instead of ds_bpermute.
template <int S>
__device__ __forceinline__ float ror16(float x) {
    return __builtin_bit_cast(float, __builtin_amdgcn_update_dpp(
        0, __builtin_bit_cast(int, x), 0x120 | S, 0xF, 0xF, true));
}
__device__ __forceinline__ float row_max16(float x) {
    x = fmaxf(x, ror16<8>(x));
    x = fmaxf(x, ror16<4>(x));
    x = fmaxf(x, ror16<2>(x));
    x = fmaxf(x, ror16<1>(x));
    return x;
}
__device__ __forceinline__ float row_sum16(float x) {
    x += ror16<8>(x);
    x += ror16<4>(x);
    x += ror16<2>(x);
    x += ror16<1>(x);
    return x;
}

// ---------------------------------------------------------------------------
// fp32 -> bf16 convert
// ---------------------------------------------------------------------------
__global__ __launch_bounds__(256) void cvt_bf16(const float* __restrict__ in,
                                                __bf16* __restrict__ out, int n4) {
    int i = blockIdx.x * 256 + threadIdx.x;
    if (i < n4) {
        float4 v = reinterpret_cast<const float4*>(in)[i];
        bf16x4 o = {(__bf16)v.x, (__bf16)v.y, (__bf16)v.z, (__bf16)v.w};
        reinterpret_cast<bf16x4*>(out)[i] = o;
    }
}

// ---------------------------------------------------------------------------
// bf16 MFMA NT GEMM (m97 structure): C[M,N] = A[M,K] * W[N,K]^T
// ---------------------------------------------------------------------------
template <typename CT>
__global__ __launch_bounds__(256) void gemm_bf16_nt(const __bf16* __restrict__ A,
                                                    const __bf16* __restrict__ W,
                                                    CT* __restrict__ C,
                                                    int M, int N, int K) {
    __shared__ __bf16 As[128 * 32];
    __shared__ __bf16 Bs[128 * 32];

    const int t    = threadIdx.x;
    const int w    = t >> 6;
    const int lane = t & 63;
    const int col  = lane & 15;
    const int quad = lane >> 4;
    const int wm   = w >> 1;
    const int wn   = w & 1;

    const int m0 = blockIdx.y * 128;
    const int n0 = blockIdx.x * 128;

    const int lrow = lane >> 2;
    const int lk   = (lane & 3) * 8;

    const __bf16* agp = A + (size_t)(m0 + w * 32 + lrow) * K + lk;
    const __bf16* wgp = W + (size_t)(n0 + w * 32 + lrow) * K + lk;
    __bf16* alp = As + (w * 32) * 32;
    __bf16* blp = Bs + (w * 32) * 32;

    f32x4 acc[4][4];
    #pragma unroll
    for (int m = 0; m < 4; m++)
        #pragma unroll
        for (int n = 0; n < 4; n++) acc[m][n] = (f32x4){0.f, 0.f, 0.f, 0.f};

    #pragma unroll 1
    for (int k0 = 0; k0 < K; k0 += 32) {
        __builtin_amdgcn_global_load_lds(AS1(agp + k0),                  AS3(alp),           16, 0, 0);
        __builtin_amdgcn_global_load_lds(AS1(agp + k0 + (size_t)16 * K), AS3(alp + 16 * 32), 16, 0, 0);
        __builtin_amdgcn_global_load_lds(AS1(wgp + k0),                  AS3(blp),           16, 0, 0);
        __builtin_amdgcn_global_load_lds(AS1(wgp + k0 + (size_t)16 * K), AS3(blp + 16 * 32), 16, 0, 0);
        __syncthreads();

        bf16x8 af[4], bfr[4];
        #pragma unroll
        for (int m = 0; m < 4; m++)
            af[m] = *reinterpret_cast<const bf16x8*>(&As[(wm * 64 + m * 16 + col) * 32 + quad * 8]);
        #pragma unroll
        for (int n = 0; n < 4; n++)
            bfr[n] = *reinterpret_cast<const bf16x8*>(&Bs[(wn * 64 + n * 16 + col) * 32 + quad * 8]);

        #pragma unroll
        for (int m = 0; m < 4; m++)
            #pragma unroll
            for (int n = 0; n < 4; n++)
                acc[m][n] = __builtin_amdgcn_mfma_f32_16x16x32_bf16(af[m], bfr[n], acc[m][n], 0, 0, 0);
        __syncthreads();
    }

    #pragma unroll
    for (int m = 0; m < 4; m++) {
        #pragma unroll
        for (int r = 0; r < 4; r++) {
            size_t row = m0 + wm * 64 + m * 16 + quad * 4 + r;
            CT* cp = C + row * N + n0 + wn * 64 + col;
            #pragma unroll
            for (int n = 0; n < 4; n++) cp[n * 16] = (CT)acc[m][n][r];
        }
    }
}

// ---------------------------------------------------------------------------
// Fused per-head RMSNorm + RoPE, in-place on bf16 qkv buffer.
// ---------------------------------------------------------------------------
__global__ __launch_bounds__(128) void norm_rope(__bf16* __restrict__ base,
                                                 const float* __restrict__ w) {
    __shared__ float sred[2];
    __shared__ float nv[128];

    const int row  = blockIdx.x;
    const int s    = row & (S_ - 1);
    const int head = blockIdx.y;
    const int d    = threadIdx.x;

    __bf16* p = base + (size_t)row * NQKV + (size_t)head * HD_;
    float x = (float)p[d];

    float ss = x * x;
    #pragma unroll
    for (int off = 32; off; off >>= 1) ss += __shfl_xor(ss, off);
    if ((threadIdx.x & 63) == 0) sred[threadIdx.x >> 6] = ss;
    __syncthreads();
    float mean = (sred[0] + sred[1]) * (1.0f / 128.0f);
    float rs = rsqrtf(mean + 1e-6f);

    float n = x * rs * w[d];
    nv[d] = n;
    __syncthreads();

    const int i = d & 63;
    float inv_freq = expf(-13.815510557964274f * (float)(2 * i) * (1.0f / 128.0f));
    float ang = (float)s * inv_freq;
    float sn, cs;
    sincosf(ang, &sn, &cs);

    float other = nv[d ^ 64];
    float r = (d < 64) ? (n * cs - other * sn)
                       : (other * sn + n * cs);
    p[d] = (__bf16)r;
}

// ---------------------------------------------------------------------------
// V transpose: vt[(b*HK+kvh)*128 + dim][s] = v[b*S+s][kvh*128+dim]
// ---------------------------------------------------------------------------
__global__ __launch_bounds__(256) void transpose_v(const __bf16* __restrict__ qkv,
                                                   __bf16* __restrict__ vt) {
    __shared__ __bf16 Ls[64][136];
    const int t  = threadIdx.x;
    const int bk = blockIdx.y;            // b*8 + kvh
    const int b  = bk >> 3;
    const int kvh = bk & 7;
    const int s0 = blockIdx.x * 64;

    #pragma unroll
    for (int i = 0; i < 4; i++) {
        int f = t + i * 256;
        int row = f >> 4;
        int d8 = (f & 15) * 8;
        bf16x8 v = *reinterpret_cast<const bf16x8*>(
            &qkv[(size_t)(b * S_ + s0 + row) * NQKV + 3072 + kvh * HD_ + d8]);
        *reinterpret_cast<bf16x8*>(&Ls[row][d8]) = v;
    }
    __syncthreads();

    #pragma unroll
    for (int i = 0; i < 4; i++) {
        int f = t + i * 256;
        int dim = f >> 3;
        int kc = f & 7;
        bf16x8 o;
        #pragma unroll
        for (int e = 0; e < 8; e++) o[e] = Ls[kc * 8 + e][dim];
        *reinterpret_cast<bf16x8*>(
            &vt[((size_t)bk * HD_ + dim) * S_ + s0 + kc * 8]) = o;
    }
}

// ---------------------------------------------------------------------------
// MFMA bf16 flash attention (causal, GQA rep=2).
// Grid: (B*H, S/64) — y is the q-tile, biggest tiles dispatched FIRST.
// Block: 256 threads = 4 waves; 64 q-rows/block, wave w owns rows
// [w*16, w*16+16). K/V tiles (64 keys) register-double-buffered across the
// barrier; softmax reductions via DPP row_ror (VALU, no LDS round-trip).
// LDS: union{ Qs[64][136] | Ks[64][136] } + Vt[128][72] + Ps[4][16][72]
//      = 17408 + 18432 + 9216 = 45056 B -> 3 blocks/CU.
// ---------------------------------------------------------------------------
__global__ __launch_bounds__(256) void attn_mfma(const __bf16* __restrict__ qkv,
                                                 const __bf16* __restrict__ vt,
                                                 __bf16* __restrict__ ao) {
    __shared__ __align__(16) char smem[17408];
    __bf16 (*Qs)[136] = reinterpret_cast<__bf16(*)[136]>(smem);
    __bf16 (*Ks)[136] = reinterpret_cast<__bf16(*)[136]>(smem);
    __shared__ __bf16 Vt[128][72];
    __shared__ __bf16 Ps[4][16][72];

    const int t    = threadIdx.x;
    const int w    = t >> 6;
    const int lane = t & 63;
    const int col  = lane & 15;
    const int quad = lane >> 4;

    const int bh  = blockIdx.x;
    const int b   = bh >> 4;
    const int h   = bh & 15;
    const int kvh = h >> 1;
    const int qb  = gridDim.y - 1 - blockIdx.y;   // big q-tiles first
    const int r0  = qb * 64;

    const __bf16* vbase = vt + ((size_t)(b * HK_ + kvh) * HD_) * S_;

    // per-thread staging addresses (fixed shape, advance per tile)
    const int krow = t >> 4;            // 0..63 within K tile (t covers 16 chunks/row? no: 256 threads * 4 iters)
    // K tile: thread handles 4 chunks f = t + i*256; row = f>>4, d8 = (f&15)*8
    const __bf16* kp[4];
    __bf16*       kw_[4];
    const __bf16* vp[4];
    __bf16*       vw_[4];
    #pragma unroll
    for (int i = 0; i < 4; i++) {
        int f = t + i * 256;
        int row = f >> 4, d8 = (f & 15) * 8;
        kp[i]  = qkv + (size_t)(b * S_ + row) * NQKV + 2048 + kvh * HD_ + d8;
        kw_[i] = &Ks[row][d8];
        int dim = f >> 3, kc = f & 7;
        vp[i]  = vbase + (size_t)dim * S_ + kc * 8;
        vw_[i] = &Vt[dim][kc * 8];
    }

    // ---- prefetch K/V tile 0 into registers ----
    bf16x8 kreg[4], vreg[4];
    #pragma unroll
    for (int i = 0; i < 4; i++) {
        kreg[i] = *reinterpret_cast<const bf16x8*>(kp[i]);  kp[i] += (size_t)64 * NQKV;
        vreg[i] = *reinterpret_cast<const bf16x8*>(vp[i]);  vp[i] += 64;
    }

    // ---- stage Q tile (64 rows x 128) into Qs (overlays Ks) ----
    #pragma unroll
    for (int i = 0; i < 4; i++) {
        int f   = t + i * 256;
        int row = f >> 4;
        int d8  = (f & 15) * 8;
        bf16x8 v = *reinterpret_cast<const bf16x8*>(
            &qkv[(size_t)(b * S_ + r0 + row) * NQKV + h * HD_ + d8]);
        *reinterpret_cast<bf16x8*>(&Qs[row][d8]) = v;
    }
    __syncthreads();

    bf16x8 qf[4];
    {
        const int m = w * 16 + col;
        #pragma unroll
        for (int k = 0; k < 4; k++)
            qf[k] = *reinterpret_cast<const bf16x8*>(&Qs[m][k * 32 + quad * 8]);
    }

    f32x4 o_acc[8];
    #pragma unroll
    for (int i = 0; i < 8; i++) o_acc[i] = (f32x4){0.f, 0.f, 0.f, 0.f};
    float m_r[4], l_r[4];
    #pragma unroll
    for (int r = 0; r < 4; r++) { m_r[r] = -INFINITY; l_r[r] = 0.f; }

    const int ntiles = qb + 1;
    for (int ti = 0; ti < ntiles; ti++) {
        __syncthreads();   // prior-tile LDS reads (and iter-0 qf grab) done

        // ---- write prefetched K/V regs into LDS ----
        #pragma unroll
        for (int i = 0; i < 4; i++) {
            *reinterpret_cast<bf16x8*>(kw_[i]) = kreg[i];
            *reinterpret_cast<bf16x8*>(vw_[i]) = vreg[i];
        }
        // ---- issue next tile's global loads (overlap with compute) ----
        if (ti + 1 < ntiles) {
            #pragma unroll
            for (int i = 0; i < 4; i++) {
                kreg[i] = *reinterpret_cast<const bf16x8*>(kp[i]);  kp[i] += (size_t)64 * NQKV;
                vreg[i] = *reinterpret_cast<const bf16x8*>(vp[i]);  vp[i] += 64;
            }
        }
        __syncthreads();

        // ---- S = Q K^T (16 q-rows x 64 keys) ----
        f32x4 s[4];
        #pragma unroll
        for (int n = 0; n < 4; n++) {
            f32x4 acc = (f32x4){0.f, 0.f, 0.f, 0.f};
            #pragma unroll
            for (int k = 0; k < 4; k++) {
                bf16x8 bf = *reinterpret_cast<const bf16x8*>(
                    &Ks[n * 16 + col][k * 32 + quad * 8]);
                acc = __builtin_amdgcn_mfma_f32_16x16x32_bf16(qf[k], bf, acc, 0, 0, 0);
            }
            s[n] = acc;
        }

        // ---- online softmax (rows = quad*4+r), DPP reductions ----
        const bool diag = (ti == qb);
        float alpha[4];
        #pragma unroll
        for (int r = 0; r < 4; r++) {
            float v0 = s[0][r] * SCALE, v1 = s[1][r] * SCALE;
            float v2 = s[2][r] * SCALE, v3 = s[3][r] * SCALE;
            if (diag) {
                int qloc = w * 16 + quad * 4 + r;
                if (0 * 16 + col > qloc) v0 = -INFINITY;
                if (1 * 16 + col > qloc) v1 = -INFINITY;
                if (2 * 16 + col > qloc) v2 = -INFINITY;
                if (3 * 16 + col > qloc) v3 = -INFINITY;
            }
            float mx = row_max16(fmaxf(fmaxf(v0, v1), fmaxf(v2, v3)));
            float mn = fmaxf(m_r[r], mx);
            float al = __expf(m_r[r] - mn);
            float p0 = __expf(v0 - mn);
            float p1 = __expf(v1 - mn);
            float p2 = __expf(v2 - mn);
            float p3 = __expf(v3 - mn);
            float ts = row_sum16(p0 + p1 + p2 + p3);
            l_r[r] = l_r[r] * al + ts;
            m_r[r] = mn;
            alpha[r] = al;
            Ps[w][quad * 4 + r][0 * 16 + col] = (__bf16)p0;
            Ps[w][quad * 4 + r][1 * 16 + col] = (__bf16)p1;
            Ps[w][quad * 4 + r][2 * 16 + col] = (__bf16)p2;
            Ps[w][quad * 4 + r][3 * 16 + col] = (__bf16)p3;
        }

        #pragma unroll
        for (int n = 0; n < 8; n++)
            #pragma unroll
            for (int r = 0; r < 4; r++)
                o_acc[n][r] *= alpha[r];

        // ---- PV (same-wave RAW on Ps: no barrier needed) ----
        bf16x8 pf[2];
        #pragma unroll
        for (int ks = 0; ks < 2; ks++)
            pf[ks] = *reinterpret_cast<const bf16x8*>(&Ps[w][col][ks * 32 + quad * 8]);
        #pragma unroll
        for (int n = 0; n < 8; n++) {
            #pragma unroll
            for (int ks = 0; ks < 2; ks++) {
                bf16x8 vf = *reinterpret_cast<const bf16x8*>(
                    &Vt[n * 16 + col][ks * 32 + quad * 8]);
                o_acc[n] = __builtin_amdgcn_mfma_f32_16x16x32_bf16(pf[ks], vf, o_acc[n], 0, 0, 0);
            }
        }
    }

    // ---- epilogue ----
    #pragma unroll
    for (int r = 0; r < 4; r++) {
        float inv = 1.0f / l_r[r];
        int qrow = r0 + w * 16 + quad * 4 + r;
        __bf16* op = ao + (size_t)(b * S_ + qrow) * (H_ * HD_) + h * HD_ + col;
        #pragma unroll
        for (int n = 0; n < 8; n++)
            op[n * 16] = (__bf16)(o_acc[n][r] * inv);
    }
}

// ---------------------------------------------------------------------------
extern "C" void kernel_launch(void* const* d_in, const int* in_sizes, int n_in,
                              void* d_out, int out_size, void* d_ws, size_t ws_size,
                              hipStream_t stream) {
    const float* x  = (const float*)d_in[0];
    const float* wq = (const float*)d_in[1];
    const float* wk = (const float*)d_in[2];
    const float* wv = (const float*)d_in[3];
    const float* wo = (const float*)d_in[4];
    const float* qw = (const float*)d_in[5];
    const float* kw = (const float*)d_in[6];
    float* out = (float*)d_out;

    // workspace (bf16 elements), total 50.33M elems = 100.66 MB
    __bf16* ws  = (__bf16*)d_ws;
    __bf16* xb  = ws;                               // [4096][2048]  8.4M
    __bf16* wb  = xb  + (size_t)8388608;            // [4096][2048]  8.4M (wq|wk|wv)
    __bf16* wob = wb  + (size_t)8388608;            // [2048][2048]  4.2M
    __bf16* qkv = wob + (size_t)4194304;            // [4096][4096] 16.8M
    __bf16* ao  = qkv + (size_t)16777216;           // [4096][2048]  8.4M
    __bf16* vtg = ao  + (size_t)8388608;            // [16][128][2048] 4.2M

    cvt_bf16<<<2097152 / 256, 256, 0, stream>>>(x,  xb,  2097152);
    cvt_bf16<<<1048576 / 256, 256, 0, stream>>>(wq, wb,  1048576);
    cvt_bf16<<< 524288 / 256, 256, 0, stream>>>(wk, wb + (size_t)2048 * 2048, 524288);
    cvt_bf16<<< 524288 / 256, 256, 0, stream>>>(wv, wb + (size_t)3072 * 2048, 524288);
    cvt_bf16<<<1048576 / 256, 256, 0, stream>>>(wo, wob, 1048576);

    // fused QKV projection
    gemm_bf16_nt<__bf16><<<dim3(NQKV / 128, BS_ / 128), 256, 0, stream>>>(
        xb, wb, qkv, BS_, NQKV, D_);

    // RMSNorm + RoPE on q and k
    norm_rope<<<dim3(BS_, H_),  128, 0, stream>>>(qkv,        qw);
    norm_rope<<<dim3(BS_, HK_), 128, 0, stream>>>(qkv + 2048, kw);

    // global V^T
    transpose_v<<<dim3(S_ / 64, B_ * HK_), 256, 0, stream>>>(qkv, vtg);

    // causal GQA attention (x = bh, y = q-tile big-first)
    attn_mfma<<<dim3(B_ * H_, S_ / 64), 256, 0, stream>>>(qkv, vtg, ao);

    // output projection
    gemm_bf16_nt<float><<<dim3(D_ / 128, BS_ / 128), 256, 0, stream>>>(
        ao, wob, out, BS_, D_, H_ * HD_);
}

// Round 7
// 399.610 us; speedup vs baseline: 1.6327x; 1.0516x over previous
//
#include <hip/hip_runtime.h>
#include <hip/hip_bf16.h>
#include <math.h>

// Problem constants (Qwen3-style attention block)
#define B_   2
#define S_   2048
#define D_   2048
#define H_   16
#define HK_  8
#define HD_  128
#define BS_  (B_ * S_)          // 4096 rows
#define NQKV 4096               // combined q(2048) + k(1024) + v(1024) cols
#define SCALE 0.08838834764831845f  // 1/sqrt(128)

typedef __bf16 bf16x8 __attribute__((ext_vector_type(8)));
typedef __bf16 bf16x4 __attribute__((ext_vector_type(4)));
typedef float  f32x4  __attribute__((ext_vector_type(4)));

#define AS1(p) ((const __attribute__((address_space(1))) void*)(p))
#define AS3(p) ((__attribute__((address_space(3))) void*)(p))

// 16-lane (DPP row) rotate-reduce: VALU latency instead of ds_bpermute.
template <int S>
__device__ __forceinline__ float ror16(float x) {
    return __builtin_bit_cast(float, __builtin_amdgcn_update_dpp(
        0, __builtin_bit_cast(int, x), 0x120 | S, 0xF, 0xF, true));
}
__device__ __forceinline__ float row_max16(float x) {
    x = fmaxf(x, ror16<8>(x));
    x = fmaxf(x, ror16<4>(x));
    x = fmaxf(x, ror16<2>(x));
    x = fmaxf(x, ror16<1>(x));
    return x;
}
__device__ __forceinline__ float row_sum16(float x) {
    x += ror16<8>(x);
    x += ror16<4>(x);
    x += ror16<2>(x);
    x += ror16<1>(x);
    return x;
}

// ---------------------------------------------------------------------------
// fp32 -> bf16 convert (x activation)
// ---------------------------------------------------------------------------
__global__ __launch_bounds__(256) void cvt_bf16(const float* __restrict__ in,
                                                __bf16* __restrict__ out, int n4) {
    int i = blockIdx.x * 256 + threadIdx.x;
    if (i < n4) {
        float4 v = reinterpret_cast<const float4*>(in)[i];
        bf16x4 o = {(__bf16)v.x, (__bf16)v.y, (__bf16)v.z, (__bf16)v.w};
        reinterpret_cast<bf16x4*>(out)[i] = o;
    }
}

// ---------------------------------------------------------------------------
// All-weights fp32 -> bf16 convert: wq|wk|wv into wb, wo into wob.
// Block ranges (float4 units, 256/blk): wq 4096, wk 2048, wv 2048, wo 4096.
// ---------------------------------------------------------------------------
__global__ __launch_bounds__(256) void cvt_weights(const float* __restrict__ wq,
                                                   const float* __restrict__ wk,
                                                   const float* __restrict__ wv,
                                                   const float* __restrict__ wo,
                                                   __bf16* __restrict__ wb,
                                                   __bf16* __restrict__ wob) {
    int bid = blockIdx.x;
    const float* src;
    __bf16* dst;
    int i4;
    if (bid < 4096)      { src = wq; dst = wb;                     i4 = bid * 256; }
    else if (bid < 6144) { src = wk; dst = wb + (size_t)4194304;   i4 = (bid - 4096) * 256; }
    else if (bid < 8192) { src = wv; dst = wb + (size_t)6291456;   i4 = (bid - 6144) * 256; }
    else                 { src = wo; dst = wob;                    i4 = (bid - 8192) * 256; }
    i4 += threadIdx.x;
    float4 v = reinterpret_cast<const float4*>(src)[i4];
    bf16x4 o = {(__bf16)v.x, (__bf16)v.y, (__bf16)v.z, (__bf16)v.w};
    reinterpret_cast<bf16x4*>(dst)[i4] = o;
}

// ---------------------------------------------------------------------------
// bf16 MFMA NT GEMM: C[M,N] = A[M,K] * W[N,K]^T
// 128x128 tile, BK=64 (32 MFMA per barrier-pair), 256 threads = 4 waves (2x2),
// global_load_lds width=16 staging, kk-outer fragment loop.
// LDS: 2 x 128x64 bf16 = 32 KiB.
// ---------------------------------------------------------------------------
template <typename CT>
__global__ __launch_bounds__(256) void gemm_bf16_nt(const __bf16* __restrict__ A,
                                                    const __bf16* __restrict__ W,
                                                    CT* __restrict__ C,
                                                    int M, int N, int K) {
    __shared__ __bf16 As[128 * 64];
    __shared__ __bf16 Bs[128 * 64];

    const int t    = threadIdx.x;
    const int w    = t >> 6;
    const int lane = t & 63;
    const int col  = lane & 15;
    const int quad = lane >> 4;
    const int wm   = w >> 1;
    const int wn   = w & 1;

    const int m0 = blockIdx.y * 128;
    const int n0 = blockIdx.x * 128;

    // staging: wave w covers tile rows [w*32, w*32+32), 4 issues of 8 rows.
    const int lrow8 = lane >> 3;         // 0..7
    const int lch   = (lane & 7) * 8;    // bf16 elem offset within BK=64

    const __bf16* agp = A + (size_t)(m0 + w * 32 + lrow8) * K + lch;
    const __bf16* wgp = W + (size_t)(n0 + w * 32 + lrow8) * K + lch;
    __bf16* alp = As + (w * 32) * 64;    // wave-uniform LDS bases
    __bf16* blp = Bs + (w * 32) * 64;

    f32x4 acc[4][4];
    #pragma unroll
    for (int m = 0; m < 4; m++)
        #pragma unroll
        for (int n = 0; n < 4; n++) acc[m][n] = (f32x4){0.f, 0.f, 0.f, 0.f};

    #pragma unroll 1
    for (int k0 = 0; k0 < K; k0 += 64) {
        #pragma unroll
        for (int j = 0; j < 4; j++) {
            __builtin_amdgcn_global_load_lds(AS1(agp + k0 + (size_t)(j * 8) * K),
                                             AS3(alp + j * 512), 16, 0, 0);
            __builtin_amdgcn_global_load_lds(AS1(wgp + k0 + (size_t)(j * 8) * K),
                                             AS3(blp + j * 512), 16, 0, 0);
        }
        __syncthreads();

        #pragma unroll
        for (int kk = 0; kk < 2; kk++) {
            bf16x8 af[4], bfr[4];
            #pragma unroll
            for (int m = 0; m < 4; m++)
                af[m] = *reinterpret_cast<const bf16x8*>(
                    &As[(wm * 64 + m * 16 + col) * 64 + kk * 32 + quad * 8]);
            #pragma unroll
            for (int n = 0; n < 4; n++)
                bfr[n] = *reinterpret_cast<const bf16x8*>(
                    &Bs[(wn * 64 + n * 16 + col) * 64 + kk * 32 + quad * 8]);

            #pragma unroll
            for (int m = 0; m < 4; m++)
                #pragma unroll
                for (int n = 0; n < 4; n++)
                    acc[m][n] = __builtin_amdgcn_mfma_f32_16x16x32_bf16(af[m], bfr[n], acc[m][n], 0, 0, 0);
        }
        __syncthreads();
    }

    // epilogue: C/D layout col=lane&15, row=quad*4+reg
    #pragma unroll
    for (int m = 0; m < 4; m++) {
        #pragma unroll
        for (int r = 0; r < 4; r++) {
            size_t row = m0 + wm * 64 + m * 16 + quad * 4 + r;
            CT* cp = C + row * N + n0 + wn * 64 + col;
            #pragma unroll
            for (int n = 0; n < 4; n++) cp[n * 16] = (CT)acc[m][n][r];
        }
    }
}

// ---------------------------------------------------------------------------
// Fused per-head RMSNorm + RoPE for q AND k in one launch.
// Grid (BS, 24): head<16 -> q head, else k head-16 (base +2048).
// ---------------------------------------------------------------------------
__global__ __launch_bounds__(128) void norm_rope(__bf16* __restrict__ qkv,
                                                 const float* __restrict__ qw,
                                                 const float* __restrict__ kw) {
    __shared__ float sred[2];
    __shared__ float nv[128];

    const int row  = blockIdx.x;
    const int s    = row & (S_ - 1);
    const int head = blockIdx.y;
    const int d    = threadIdx.x;

    const bool isq = head < H_;
    const float* w = isq ? qw : kw;
    __bf16* p = qkv + (size_t)row * NQKV
              + (isq ? (size_t)head * HD_ : (size_t)2048 + (size_t)(head - H_) * HD_);
    float x = (float)p[d];

    float ss = x * x;
    #pragma unroll
    for (int off = 32; off; off >>= 1) ss += __shfl_xor(ss, off);
    if ((threadIdx.x & 63) == 0) sred[threadIdx.x >> 6] = ss;
    __syncthreads();
    float mean = (sred[0] + sred[1]) * (1.0f / 128.0f);
    float rs = rsqrtf(mean + 1e-6f);

    float n = x * rs * w[d];
    nv[d] = n;
    __syncthreads();

    const int i = d & 63;
    float inv_freq = expf(-13.815510557964274f * (float)(2 * i) * (1.0f / 128.0f));
    float ang = (float)s * inv_freq;
    float sn, cs;
    sincosf(ang, &sn, &cs);

    float other = nv[d ^ 64];
    float r = (d < 64) ? (n * cs - other * sn)
                       : (other * sn + n * cs);
    p[d] = (__bf16)r;
}

// ---------------------------------------------------------------------------
// V transpose: vt[(b*HK+kvh)*128 + dim][s] = v[b*S+s][kvh*128+dim]
// ---------------------------------------------------------------------------
__global__ __launch_bounds__(256) void transpose_v(const __bf16* __restrict__ qkv,
                                                   __bf16* __restrict__ vt) {
    __shared__ __bf16 Ls[64][136];
    const int t  = threadIdx.x;
    const int bk = blockIdx.y;            // b*8 + kvh
    const int b  = bk >> 3;
    const int kvh = bk & 7;
    const int s0 = blockIdx.x * 64;

    #pragma unroll
    for (int i = 0; i < 4; i++) {
        int f = t + i * 256;
        int row = f >> 4;
        int d8 = (f & 15) * 8;
        bf16x8 v = *reinterpret_cast<const bf16x8*>(
            &qkv[(size_t)(b * S_ + s0 + row) * NQKV + 3072 + kvh * HD_ + d8]);
        *reinterpret_cast<bf16x8*>(&Ls[row][d8]) = v;
    }
    __syncthreads();

    #pragma unroll
    for (int i = 0; i < 4; i++) {
        int f = t + i * 256;
        int dim = f >> 3;
        int kc = f & 7;
        bf16x8 o;
        #pragma unroll
        for (int e = 0; e < 8; e++) o[e] = Ls[kc * 8 + e][dim];
        *reinterpret_cast<bf16x8*>(
            &vt[((size_t)bk * HD_ + dim) * S_ + s0 + kc * 8]) = o;
    }
}

// ---------------------------------------------------------------------------
// MFMA bf16 flash attention (causal, GQA rep=2).
// Grid: (B*H, S/64) — y is the q-tile, biggest tiles dispatched FIRST.
// Block: 256 threads = 4 waves; 64 q-rows/block, wave w owns rows
// [w*16, w*16+16). K/V tiles (64 keys) register-double-buffered across the
// barrier; softmax reductions via DPP row_ror (VALU, no LDS round-trip).
// LDS: union{ Qs[64][136] | Ks[64][136] } + Vt[128][72] + Ps[4][16][72]
//      = 17408 + 18432 + 9216 = 45056 B -> 3 blocks/CU.
// ---------------------------------------------------------------------------
__global__ __launch_bounds__(256) void attn_mfma(const __bf16* __restrict__ qkv,
                                                 const __bf16* __restrict__ vt,
                                                 __bf16* __restrict__ ao) {
    __shared__ __align__(16) char smem[17408];
    __bf16 (*Qs)[136] = reinterpret_cast<__bf16(*)[136]>(smem);
    __bf16 (*Ks)[136] = reinterpret_cast<__bf16(*)[136]>(smem);
    __shared__ __bf16 Vt[128][72];
    __shared__ __bf16 Ps[4][16][72];

    const int t    = threadIdx.x;
    const int w    = t >> 6;
    const int lane = t & 63;
    const int col  = lane & 15;
    const int quad = lane >> 4;

    const int bh  = blockIdx.x;
    const int b   = bh >> 4;
    const int h   = bh & 15;
    const int kvh = h >> 1;
    const int qb  = gridDim.y - 1 - blockIdx.y;   // big q-tiles first
    const int r0  = qb * 64;

    const __bf16* vbase = vt + ((size_t)(b * HK_ + kvh) * HD_) * S_;

    // per-thread staging addresses (fixed shape, advance per tile)
    const __bf16* kp[4];
    __bf16*       kw_[4];
    const __bf16* vp[4];
    __bf16*       vw_[4];
    #pragma unroll
    for (int i = 0; i < 4; i++) {
        int f = t + i * 256;
        int row = f >> 4, d8 = (f & 15) * 8;
        kp[i]  = qkv + (size_t)(b * S_ + row) * NQKV + 2048 + kvh * HD_ + d8;
        kw_[i] = &Ks[row][d8];
        int dim = f >> 3, kc = f & 7;
        vp[i]  = vbase + (size_t)dim * S_ + kc * 8;
        vw_[i] = &Vt[dim][kc * 8];
    }

    // ---- prefetch K/V tile 0 into registers ----
    bf16x8 kreg[4], vreg[4];
    #pragma unroll
    for (int i = 0; i < 4; i++) {
        kreg[i] = *reinterpret_cast<const bf16x8*>(kp[i]);  kp[i] += (size_t)64 * NQKV;
        vreg[i] = *reinterpret_cast<const bf16x8*>(vp[i]);  vp[i] += 64;
    }

    // ---- stage Q tile (64 rows x 128) into Qs (overlays Ks) ----
    #pragma unroll
    for (int i = 0; i < 4; i++) {
        int f   = t + i * 256;
        int row = f >> 4;
        int d8  = (f & 15) * 8;
        bf16x8 v = *reinterpret_cast<const bf16x8*>(
            &qkv[(size_t)(b * S_ + r0 + row) * NQKV + h * HD_ + d8]);
        *reinterpret_cast<bf16x8*>(&Qs[row][d8]) = v;
    }
    __syncthreads();

    bf16x8 qf[4];
    {
        const int m = w * 16 + col;
        #pragma unroll
        for (int k = 0; k < 4; k++)
            qf[k] = *reinterpret_cast<const bf16x8*>(&Qs[m][k * 32 + quad * 8]);
    }

    f32x4 o_acc[8];
    #pragma unroll
    for (int i = 0; i < 8; i++) o_acc[i] = (f32x4){0.f, 0.f, 0.f, 0.f};
    float m_r[4], l_r[4];
    #pragma unroll
    for (int r = 0; r < 4; r++) { m_r[r] = -INFINITY; l_r[r] = 0.f; }

    const int ntiles = qb + 1;
    for (int ti = 0; ti < ntiles; ti++) {
        __syncthreads();   // prior-tile LDS reads (and iter-0 qf grab) done

        // ---- write prefetched K/V regs into LDS ----
        #pragma unroll
        for (int i = 0; i < 4; i++) {
            *reinterpret_cast<bf16x8*>(kw_[i]) = kreg[i];
            *reinterpret_cast<bf16x8*>(vw_[i]) = vreg[i];
        }
        // ---- issue next tile's global loads (overlap with compute) ----
        if (ti + 1 < ntiles) {
            #pragma unroll
            for (int i = 0; i < 4; i++) {
                kreg[i] = *reinterpret_cast<const bf16x8*>(kp[i]);  kp[i] += (size_t)64 * NQKV;
                vreg[i] = *reinterpret_cast<const bf16x8*>(vp[i]);  vp[i] += 64;
            }
        }
        __syncthreads();

        // ---- S = Q K^T (16 q-rows x 64 keys) ----
        f32x4 s[4];
        #pragma unroll
        for (int n = 0; n < 4; n++) {
            f32x4 acc = (f32x4){0.f, 0.f, 0.f, 0.f};
            #pragma unroll
            for (int k = 0; k < 4; k++) {
                bf16x8 bf = *reinterpret_cast<const bf16x8*>(
                    &Ks[n * 16 + col][k * 32 + quad * 8]);
                acc = __builtin_amdgcn_mfma_f32_16x16x32_bf16(qf[k], bf, acc, 0, 0, 0);
            }
            s[n] = acc;
        }

        // ---- online softmax (rows = quad*4+r), DPP reductions ----
        const bool diag = (ti == qb);
        float alpha[4];
        #pragma unroll
        for (int r = 0; r < 4; r++) {
            float v0 = s[0][r] * SCALE, v1 = s[1][r] * SCALE;
            float v2 = s[2][r] * SCALE, v3 = s[3][r] * SCALE;
            if (diag) {
                int qloc = w * 16 + quad * 4 + r;
                if (0 * 16 + col > qloc) v0 = -INFINITY;
                if (1 * 16 + col > qloc) v1 = -INFINITY;
                if (2 * 16 + col > qloc) v2 = -INFINITY;
                if (3 * 16 + col > qloc) v3 = -INFINITY;
            }
            float mx = row_max16(fmaxf(fmaxf(v0, v1), fmaxf(v2, v3)));
            float mn = fmaxf(m_r[r], mx);
            float al = __expf(m_r[r] - mn);
            float p0 = __expf(v0 - mn);
            float p1 = __expf(v1 - mn);
            float p2 = __expf(v2 - mn);
            float p3 = __expf(v3 - mn);
            float ts = row_sum16(p0 + p1 + p2 + p3);
            l_r[r] = l_r[r] * al + ts;
            m_r[r] = mn;
            alpha[r] = al;
            Ps[w][quad * 4 + r][0 * 16 + col] = (__bf16)p0;
            Ps[w][quad * 4 + r][1 * 16 + col] = (__bf16)p1;
            Ps[w][quad * 4 + r][2 * 16 + col] = (__bf16)p2;
            Ps[w][quad * 4 + r][3 * 16 + col] = (__bf16)p3;
        }

        #pragma unroll
        for (int n = 0; n < 8; n++)
            #pragma unroll
            for (int r = 0; r < 4; r++)
                o_acc[n][r] *= alpha[r];

        // ---- PV (same-wave RAW on Ps: no barrier needed) ----
        bf16x8 pf[2];
        #pragma unroll
        for (int ks = 0; ks < 2; ks++)
            pf[ks] = *reinterpret_cast<const bf16x8*>(&Ps[w][col][ks * 32 + quad * 8]);
        #pragma unroll
        for (int n = 0; n < 8; n++) {
            #pragma unroll
            for (int ks = 0; ks < 2; ks++) {
                bf16x8 vf = *reinterpret_cast<const bf16x8*>(
                    &Vt[n * 16 + col][ks * 32 + quad * 8]);
                o_acc[n] = __builtin_amdgcn_mfma_f32_16x16x32_bf16(pf[ks], vf, o_acc[n], 0, 0, 0);
            }
        }
    }

    // ---- epilogue ----
    #pragma unroll
    for (int r = 0; r < 4; r++) {
        float inv = 1.0f / l_r[r];
        int qrow = r0 + w * 16 + quad * 4 + r;
        __bf16* op = ao + (size_t)(b * S_ + qrow) * (H_ * HD_) + h * HD_ + col;
        #pragma unroll
        for (int n = 0; n < 8; n++)
            op[n * 16] = (__bf16)(o_acc[n][r] * inv);
    }
}

// ---------------------------------------------------------------------------
extern "C" void kernel_launch(void* const* d_in, const int* in_sizes, int n_in,
                              void* d_out, int out_size, void* d_ws, size_t ws_size,
                              hipStream_t stream) {
    const float* x  = (const float*)d_in[0];
    const float* wq = (const float*)d_in[1];
    const float* wk = (const float*)d_in[2];
    const float* wv = (const float*)d_in[3];
    const float* wo = (const float*)d_in[4];
    const float* qw = (const float*)d_in[5];
    const float* kw = (const float*)d_in[6];
    float* out = (float*)d_out;

    // workspace (bf16 elements), total 50.33M elems = 100.66 MB
    __bf16* ws  = (__bf16*)d_ws;
    __bf16* xb  = ws;                               // [4096][2048]  8.4M
    __bf16* wb  = xb  + (size_t)8388608;            // [4096][2048]  8.4M (wq|wk|wv)
    __bf16* wob = wb  + (size_t)8388608;            // [2048][2048]  4.2M
    __bf16* qkv = wob + (size_t)4194304;            // [4096][4096] 16.8M
    __bf16* ao  = qkv + (size_t)16777216;           // [4096][2048]  8.4M
    __bf16* vtg = ao  + (size_t)8388608;            // [16][128][2048] 4.2M

    cvt_bf16<<<8192, 256, 0, stream>>>(x, xb, 2097152);
    cvt_weights<<<12288, 256, 0, stream>>>(wq, wk, wv, wo, wb, wob);

    // fused QKV projection
    gemm_bf16_nt<__bf16><<<dim3(NQKV / 128, BS_ / 128), 256, 0, stream>>>(
        xb, wb, qkv, BS_, NQKV, D_);

    // RMSNorm + RoPE on q (heads 0..15) and k (heads 16..23), one launch
    norm_rope<<<dim3(BS_, H_ + HK_), 128, 0, stream>>>(qkv, qw, kw);

    // global V^T
    transpose_v<<<dim3(S_ / 64, B_ * HK_), 256, 0, stream>>>(qkv, vtg);

    // causal GQA attention (x = bh, y = q-tile big-first)
    attn_mfma<<<dim3(B_ * H_, S_ / 64), 256, 0, stream>>>(qkv, vtg, ao);

    // output projection
    gemm_bf16_nt<float><<<dim3(D_ / 128, BS_ / 128), 256, 0, stream>>>(
        ao, wob, out, BS_, D_, H_ * HD_);
}

// Round 8
// 379.666 us; speedup vs baseline: 1.7185x; 1.0525x over previous
//
#include <hip/hip_runtime.h>
#include <hip/hip_bf16.h>
#include <math.h>

// Problem constants (Qwen3-style attention block)
#define B_   2
#define S_   2048
#define D_   2048
#define H_   16
#define HK_  8
#define HD_  128
#define BS_  (B_ * S_)          // 4096 rows
#define NQKV 4096               // combined q(2048) + k(1024) + v(1024) cols
#define SCALE 0.08838834764831845f  // 1/sqrt(128)

typedef __bf16 bf16x8 __attribute__((ext_vector_type(8)));
typedef __bf16 bf16x4 __attribute__((ext_vector_type(4)));
typedef float  f32x4  __attribute__((ext_vector_type(4)));

#define AS1(p) ((const __attribute__((address_space(1))) void*)(p))
#define AS3(p) ((__attribute__((address_space(3))) void*)(p))

// 16-lane (DPP row) rotate-reduce: VALU latency instead of ds_bpermute.
template <int S>
__device__ __forceinline__ float ror16(float x) {
    return __builtin_bit_cast(float, __builtin_amdgcn_update_dpp(
        0, __builtin_bit_cast(int, x), 0x120 | S, 0xF, 0xF, true));
}
__device__ __forceinline__ float row_max16(float x) {
    x = fmaxf(x, ror16<8>(x));
    x = fmaxf(x, ror16<4>(x));
    x = fmaxf(x, ror16<2>(x));
    x = fmaxf(x, ror16<1>(x));
    return x;
}
__device__ __forceinline__ float row_sum16(float x) {
    x += ror16<8>(x);
    x += ror16<4>(x);
    x += ror16<2>(x);
    x += ror16<1>(x);
    return x;
}

// ---------------------------------------------------------------------------
// fp32 -> bf16 convert (x activation)
// ---------------------------------------------------------------------------
__global__ __launch_bounds__(256) void cvt_bf16(const float* __restrict__ in,
                                                __bf16* __restrict__ out, int n4) {
    int i = blockIdx.x * 256 + threadIdx.x;
    if (i < n4) {
        float4 v = reinterpret_cast<const float4*>(in)[i];
        bf16x4 o = {(__bf16)v.x, (__bf16)v.y, (__bf16)v.z, (__bf16)v.w};
        reinterpret_cast<bf16x4*>(out)[i] = o;
    }
}

// ---------------------------------------------------------------------------
// All-weights fp32 -> bf16 convert: wq|wk|wv into wb, wo into wob.
// ---------------------------------------------------------------------------
__global__ __launch_bounds__(256) void cvt_weights(const float* __restrict__ wq,
                                                   const float* __restrict__ wk,
                                                   const float* __restrict__ wv,
                                                   const float* __restrict__ wo,
                                                   __bf16* __restrict__ wb,
                                                   __bf16* __restrict__ wob) {
    int bid = blockIdx.x;
    const float* src;
    __bf16* dst;
    int i4;
    if (bid < 4096)      { src = wq; dst = wb;                     i4 = bid * 256; }
    else if (bid < 6144) { src = wk; dst = wb + (size_t)4194304;   i4 = (bid - 4096) * 256; }
    else if (bid < 8192) { src = wv; dst = wb + (size_t)6291456;   i4 = (bid - 6144) * 256; }
    else                 { src = wo; dst = wob;                    i4 = (bid - 8192) * 256; }
    i4 += threadIdx.x;
    float4 v = reinterpret_cast<const float4*>(src)[i4];
    bf16x4 o = {(__bf16)v.x, (__bf16)v.y, (__bf16)v.z, (__bf16)v.w};
    reinterpret_cast<bf16x4*>(dst)[i4] = o;
}

// ---------------------------------------------------------------------------
// bf16 MFMA NT GEMM: C[M,N] = A[M,K] * W[N,K]^T
// 128x128 tile, BK=64, 256 threads = 4 waves (2x2), global_load_lds width=16.
// XOR-swizzled LDS: lane fetches global chunk (ch ^ row&7), so physical
// chunk p of row r holds logical chunk (p ^ (r&7)). Fragment reads address
// chunk ((kk*4+quad) ^ (col&7)) -> banks spread 8-wide, 2-way = free.
// LDS: 2 x 128x64 bf16 = 32 KiB.
// ---------------------------------------------------------------------------
template <typename CT>
__global__ __launch_bounds__(256) void gemm_bf16_nt(const __bf16* __restrict__ A,
                                                    const __bf16* __restrict__ W,
                                                    CT* __restrict__ C,
                                                    int M, int N, int K) {
    __shared__ __bf16 As[128 * 64];
    __shared__ __bf16 Bs[128 * 64];

    const int t    = threadIdx.x;
    const int w    = t >> 6;
    const int lane = t & 63;
    const int col  = lane & 15;
    const int quad = lane >> 4;
    const int wm   = w >> 1;
    const int wn   = w & 1;

    const int m0 = blockIdx.y * 128;
    const int n0 = blockIdx.x * 128;

    // staging: wave w covers tile rows [w*32, w*32+32), 4 issues of 8 rows.
    const int lrow8 = lane >> 3;                     // 0..7
    const int lch   = ((lane & 7) ^ lrow8) * 8;      // swizzled K-chunk

    const __bf16* agp = A + (size_t)(m0 + w * 32 + lrow8) * K + lch;
    const __bf16* wgp = W + (size_t)(n0 + w * 32 + lrow8) * K + lch;
    __bf16* alp = As + (w * 32) * 64;    // wave-uniform LDS bases
    __bf16* blp = Bs + (w * 32) * 64;

    const int c7 = col & 7;              // swizzle key for fragment reads

    f32x4 acc[4][4];
    #pragma unroll
    for (int m = 0; m < 4; m++)
        #pragma unroll
        for (int n = 0; n < 4; n++) acc[m][n] = (f32x4){0.f, 0.f, 0.f, 0.f};

    #pragma unroll 1
    for (int k0 = 0; k0 < K; k0 += 64) {
        #pragma unroll
        for (int j = 0; j < 4; j++) {
            __builtin_amdgcn_global_load_lds(AS1(agp + k0 + (size_t)(j * 8) * K),
                                             AS3(alp + j * 512), 16, 0, 0);
            __builtin_amdgcn_global_load_lds(AS1(wgp + k0 + (size_t)(j * 8) * K),
                                             AS3(blp + j * 512), 16, 0, 0);
        }
        __syncthreads();

        #pragma unroll
        for (int kk = 0; kk < 2; kk++) {
            bf16x8 af[4], bfr[4];
            #pragma unroll
            for (int m = 0; m < 4; m++)
                af[m] = *reinterpret_cast<const bf16x8*>(
                    &As[(wm * 64 + m * 16 + col) * 64 + ((kk * 4 + quad) ^ c7) * 8]);
            #pragma unroll
            for (int n = 0; n < 4; n++)
                bfr[n] = *reinterpret_cast<const bf16x8*>(
                    &Bs[(wn * 64 + n * 16 + col) * 64 + ((kk * 4 + quad) ^ c7) * 8]);

            #pragma unroll
            for (int m = 0; m < 4; m++)
                #pragma unroll
                for (int n = 0; n < 4; n++)
                    acc[m][n] = __builtin_amdgcn_mfma_f32_16x16x32_bf16(af[m], bfr[n], acc[m][n], 0, 0, 0);
        }
        __syncthreads();
    }

    // epilogue: C/D layout col=lane&15, row=quad*4+reg
    #pragma unroll
    for (int m = 0; m < 4; m++) {
        #pragma unroll
        for (int r = 0; r < 4; r++) {
            size_t row = m0 + wm * 64 + m * 16 + quad * 4 + r;
            CT* cp = C + row * N + n0 + wn * 64 + col;
            #pragma unroll
            for (int n = 0; n < 4; n++) cp[n * 16] = (CT)acc[m][n][r];
        }
    }
}

// ---------------------------------------------------------------------------
// Fused per-head RMSNorm + RoPE for q AND k in one launch.
// Grid (BS, 24): head<16 -> q head, else k head-16 (base +2048).
// ---------------------------------------------------------------------------
__global__ __launch_bounds__(128) void norm_rope(__bf16* __restrict__ qkv,
                                                 const float* __restrict__ qw,
                                                 const float* __restrict__ kw) {
    __shared__ float sred[2];
    __shared__ float nv[128];

    const int row  = blockIdx.x;
    const int s    = row & (S_ - 1);
    const int head = blockIdx.y;
    const int d    = threadIdx.x;

    const bool isq = head < H_;
    const float* w = isq ? qw : kw;
    __bf16* p = qkv + (size_t)row * NQKV
              + (isq ? (size_t)head * HD_ : (size_t)2048 + (size_t)(head - H_) * HD_);
    float x = (float)p[d];

    float ss = x * x;
    #pragma unroll
    for (int off = 32; off; off >>= 1) ss += __shfl_xor(ss, off);
    if ((threadIdx.x & 63) == 0) sred[threadIdx.x >> 6] = ss;
    __syncthreads();
    float mean = (sred[0] + sred[1]) * (1.0f / 128.0f);
    float rs = rsqrtf(mean + 1e-6f);

    float n = x * rs * w[d];
    nv[d] = n;
    __syncthreads();

    const int i = d & 63;
    float inv_freq = expf(-13.815510557964274f * (float)(2 * i) * (1.0f / 128.0f));
    float ang = (float)s * inv_freq;
    float sn, cs;
    sincosf(ang, &sn, &cs);

    float other = nv[d ^ 64];
    float r = (d < 64) ? (n * cs - other * sn)
                       : (other * sn + n * cs);
    p[d] = (__bf16)r;
}

// ---------------------------------------------------------------------------
// V transpose: vt[(b*HK+kvh)*128 + dim][s] = v[b*S+s][kvh*128+dim]
// ---------------------------------------------------------------------------
__global__ __launch_bounds__(256) void transpose_v(const __bf16* __restrict__ qkv,
                                                   __bf16* __restrict__ vt) {
    __shared__ __bf16 Ls[64][136];
    const int t  = threadIdx.x;
    const int bk = blockIdx.y;            // b*8 + kvh
    const int b  = bk >> 3;
    const int kvh = bk & 7;
    const int s0 = blockIdx.x * 64;

    #pragma unroll
    for (int i = 0; i < 4; i++) {
        int f = t + i * 256;
        int row = f >> 4;
        int d8 = (f & 15) * 8;
        bf16x8 v = *reinterpret_cast<const bf16x8*>(
            &qkv[(size_t)(b * S_ + s0 + row) * NQKV + 3072 + kvh * HD_ + d8]);
        *reinterpret_cast<bf16x8*>(&Ls[row][d8]) = v;
    }
    __syncthreads();

    #pragma unroll
    for (int i = 0; i < 4; i++) {
        int f = t + i * 256;
        int dim = f >> 3;
        int kc = f & 7;
        bf16x8 o;
        #pragma unroll
        for (int e = 0; e < 8; e++) o[e] = Ls[kc * 8 + e][dim];
        *reinterpret_cast<bf16x8*>(
            &vt[((size_t)bk * HD_ + dim) * S_ + s0 + kc * 8]) = o;
    }
}

// ---------------------------------------------------------------------------
// MFMA bf16 flash attention (causal, GQA rep=2).
// Grid: (B*H, S/64) — y is the q-tile, biggest tiles dispatched FIRST.
// Block: 256 threads = 4 waves; 64 q-rows/block. K/V tiles (64 keys)
// register-double-buffered across the barrier; DPP softmax reductions.
// LDS: union{ Qs | Ks } + Vt + Ps = 45056 B -> 3 blocks/CU.
// ---------------------------------------------------------------------------
__global__ __launch_bounds__(256) void attn_mfma(const __bf16* __restrict__ qkv,
                                                 const __bf16* __restrict__ vt,
                                                 __bf16* __restrict__ ao) {
    __shared__ __align__(16) char smem[17408];
    __bf16 (*Qs)[136] = reinterpret_cast<__bf16(*)[136]>(smem);
    __bf16 (*Ks)[136] = reinterpret_cast<__bf16(*)[136]>(smem);
    __shared__ __bf16 Vt[128][72];
    __shared__ __bf16 Ps[4][16][72];

    const int t    = threadIdx.x;
    const int w    = t >> 6;
    const int lane = t & 63;
    const int col  = lane & 15;
    const int quad = lane >> 4;

    const int bh  = blockIdx.x;
    const int b   = bh >> 4;
    const int h   = bh & 15;
    const int kvh = h >> 1;
    const int qb  = gridDim.y - 1 - blockIdx.y;   // big q-tiles first
    const int r0  = qb * 64;

    const __bf16* vbase = vt + ((size_t)(b * HK_ + kvh) * HD_) * S_;

    // per-thread staging addresses (fixed shape, advance per tile)
    const __bf16* kp[4];
    __bf16*       kw_[4];
    const __bf16* vp[4];
    __bf16*       vw_[4];
    #pragma unroll
    for (int i = 0; i < 4; i++) {
        int f = t + i * 256;
        int row = f >> 4, d8 = (f & 15) * 8;
        kp[i]  = qkv + (size_t)(b * S_ + row) * NQKV + 2048 + kvh * HD_ + d8;
        kw_[i] = &Ks[row][d8];
        int dim = f >> 3, kc = f & 7;
        vp[i]  = vbase + (size_t)dim * S_ + kc * 8;
        vw_[i] = &Vt[dim][kc * 8];
    }

    // ---- prefetch K/V tile 0 into registers ----
    bf16x8 kreg[4], vreg[4];
    #pragma unroll
    for (int i = 0; i < 4; i++) {
        kreg[i] = *reinterpret_cast<const bf16x8*>(kp[i]);  kp[i] += (size_t)64 * NQKV;
        vreg[i] = *reinterpret_cast<const bf16x8*>(vp[i]);  vp[i] += 64;
    }

    // ---- stage Q tile (64 rows x 128) into Qs (overlays Ks) ----
    #pragma unroll
    for (int i = 0; i < 4; i++) {
        int f   = t + i * 256;
        int row = f >> 4;
        int d8  = (f & 15) * 8;
        bf16x8 v = *reinterpret_cast<const bf16x8*>(
            &qkv[(size_t)(b * S_ + r0 + row) * NQKV + h * HD_ + d8]);
        *reinterpret_cast<bf16x8*>(&Qs[row][d8]) = v;
    }
    __syncthreads();

    bf16x8 qf[4];
    {
        const int m = w * 16 + col;
        #pragma unroll
        for (int k = 0; k < 4; k++)
            qf[k] = *reinterpret_cast<const bf16x8*>(&Qs[m][k * 32 + quad * 8]);
    }

    f32x4 o_acc[8];
    #pragma unroll
    for (int i = 0; i < 8; i++) o_acc[i] = (f32x4){0.f, 0.f, 0.f, 0.f};
    float m_r[4], l_r[4];
    #pragma unroll
    for (int r = 0; r < 4; r++) { m_r[r] = -INFINITY; l_r[r] = 0.f; }

    const int ntiles = qb + 1;
    for (int ti = 0; ti < ntiles; ti++) {
        __syncthreads();   // prior-tile LDS reads (and iter-0 qf grab) done

        // ---- write prefetched K/V regs into LDS ----
        #pragma unroll
        for (int i = 0; i < 4; i++) {
            *reinterpret_cast<bf16x8*>(kw_[i]) = kreg[i];
            *reinterpret_cast<bf16x8*>(vw_[i]) = vreg[i];
        }
        // ---- issue next tile's global loads (overlap with compute) ----
        if (ti + 1 < ntiles) {
            #pragma unroll
            for (int i = 0; i < 4; i++) {
                kreg[i] = *reinterpret_cast<const bf16x8*>(kp[i]);  kp[i] += (size_t)64 * NQKV;
                vreg[i] = *reinterpret_cast<const bf16x8*>(vp[i]);  vp[i] += 64;
            }
        }
        __syncthreads();

        // ---- S = Q K^T (16 q-rows x 64 keys) ----
        f32x4 s[4];
        #pragma unroll
        for (int n = 0; n < 4; n++) {
            f32x4 acc = (f32x4){0.f, 0.f, 0.f, 0.f};
            #pragma unroll
            for (int k = 0; k < 4; k++) {
                bf16x8 bf = *reinterpret_cast<const bf16x8*>(
                    &Ks[n * 16 + col][k * 32 + quad * 8]);
                acc = __builtin_amdgcn_mfma_f32_16x16x32_bf16(qf[k], bf, acc, 0, 0, 0);
            }
            s[n] = acc;
        }

        // ---- online softmax (rows = quad*4+r), DPP reductions ----
        const bool diag = (ti == qb);
        float alpha[4];
        #pragma unroll
        for (int r = 0; r < 4; r++) {
            float v0 = s[0][r] * SCALE, v1 = s[1][r] * SCALE;
            float v2 = s[2][r] * SCALE, v3 = s[3][r] * SCALE;
            if (diag) {
                int qloc = w * 16 + quad * 4 + r;
                if (0 * 16 + col > qloc) v0 = -INFINITY;
                if (1 * 16 + col > qloc) v1 = -INFINITY;
                if (2 * 16 + col > qloc) v2 = -INFINITY;
                if (3 * 16 + col > qloc) v3 = -INFINITY;
            }
            float mx = row_max16(fmaxf(fmaxf(v0, v1), fmaxf(v2, v3)));
            float mn = fmaxf(m_r[r], mx);
            float al = __expf(m_r[r] - mn);
            float p0 = __expf(v0 - mn);
            float p1 = __expf(v1 - mn);
            float p2 = __expf(v2 - mn);
            float p3 = __expf(v3 - mn);
            float ts = row_sum16(p0 + p1 + p2 + p3);
            l_r[r] = l_r[r] * al + ts;
            m_r[r] = mn;
            alpha[r] = al;
            Ps[w][quad * 4 + r][0 * 16 + col] = (__bf16)p0;
            Ps[w][quad * 4 + r][1 * 16 + col] = (__bf16)p1;
            Ps[w][quad * 4 + r][2 * 16 + col] = (__bf16)p2;
            Ps[w][quad * 4 + r][3 * 16 + col] = (__bf16)p3;
        }

        #pragma unroll
        for (int n = 0; n < 8; n++)
            #pragma unroll
            for (int r = 0; r < 4; r++)
                o_acc[n][r] *= alpha[r];

        // ---- PV (same-wave RAW on Ps: no barrier needed) ----
        bf16x8 pf[2];
        #pragma unroll
        for (int ks = 0; ks < 2; ks++)
            pf[ks] = *reinterpret_cast<const bf16x8*>(&Ps[w][col][ks * 32 + quad * 8]);
        #pragma unroll
        for (int n = 0; n < 8; n++) {
            #pragma unroll
            for (int ks = 0; ks < 2; ks++) {
                bf16x8 vf = *reinterpret_cast<const bf16x8*>(
                    &Vt[n * 16 + col][ks * 32 + quad * 8]);
                o_acc[n] = __builtin_amdgcn_mfma_f32_16x16x32_bf16(pf[ks], vf, o_acc[n], 0, 0, 0);
            }
        }
    }

    // ---- epilogue ----
    #pragma unroll
    for (int r = 0; r < 4; r++) {
        float inv = 1.0f / l_r[r];
        int qrow = r0 + w * 16 + quad * 4 + r;
        __bf16* op = ao + (size_t)(b * S_ + qrow) * (H_ * HD_) + h * HD_ + col;
        #pragma unroll
        for (int n = 0; n < 8; n++)
            op[n * 16] = (__bf16)(o_acc[n][r] * inv);
    }
}

// ---------------------------------------------------------------------------
extern "C" void kernel_launch(void* const* d_in, const int* in_sizes, int n_in,
                              void* d_out, int out_size, void* d_ws, size_t ws_size,
                              hipStream_t stream) {
    const float* x  = (const float*)d_in[0];
    const float* wq = (const float*)d_in[1];
    const float* wk = (const float*)d_in[2];
    const float* wv = (const float*)d_in[3];
    const float* wo = (const float*)d_in[4];
    const float* qw = (const float*)d_in[5];
    const float* kw = (const float*)d_in[6];
    float* out = (float*)d_out;

    // workspace (bf16 elements), total 50.33M elems = 100.66 MB
    __bf16* ws  = (__bf16*)d_ws;
    __bf16* xb  = ws;                               // [4096][2048]  8.4M
    __bf16* wb  = xb  + (size_t)8388608;            // [4096][2048]  8.4M (wq|wk|wv)
    __bf16* wob = wb  + (size_t)8388608;            // [2048][2048]  4.2M
    __bf16* qkv = wob + (size_t)4194304;            // [4096][4096] 16.8M
    __bf16* ao  = qkv + (size_t)16777216;           // [4096][2048]  8.4M
    __bf16* vtg = ao  + (size_t)8388608;            // [16][128][2048] 4.2M

    cvt_bf16<<<8192, 256, 0, stream>>>(x, xb, 2097152);
    cvt_weights<<<12288, 256, 0, stream>>>(wq, wk, wv, wo, wb, wob);

    // fused QKV projection
    gemm_bf16_nt<__bf16><<<dim3(NQKV / 128, BS_ / 128), 256, 0, stream>>>(
        xb, wb, qkv, BS_, NQKV, D_);

    // RMSNorm + RoPE on q (heads 0..15) and k (heads 16..23), one launch
    norm_rope<<<dim3(BS_, H_ + HK_), 128, 0, stream>>>(qkv, qw, kw);

    // global V^T
    transpose_v<<<dim3(S_ / 64, B_ * HK_), 256, 0, stream>>>(qkv, vtg);

    // causal GQA attention (x = bh, y = q-tile big-first)
    attn_mfma<<<dim3(B_ * H_, S_ / 64), 256, 0, stream>>>(qkv, vtg, ao);

    // output projection
    gemm_bf16_nt<float><<<dim3(D_ / 128, BS_ / 128), 256, 0, stream>>>(
        ao, wob, out, BS_, D_, H_ * HD_);
}

// Round 9
// 367.109 us; speedup vs baseline: 1.7773x; 1.0342x over previous
//
#include <hip/hip_runtime.h>
#include <hip/hip_bf16.h>
#include <math.h>

// Problem constants (Qwen3-style attention block)
#define B_   2
#define S_   2048
#define D_   2048
#define H_   16
#define HK_  8
#define HD_  128
#define BS_  (B_ * S_)          // 4096 rows
#define NQKV 4096               // combined q(2048) + k(1024) + v(1024) cols
#define SCALE 0.08838834764831845f  // 1/sqrt(128)

typedef __bf16 bf16x8 __attribute__((ext_vector_type(8)));
typedef __bf16 bf16x4 __attribute__((ext_vector_type(4)));
typedef float  f32x4  __attribute__((ext_vector_type(4)));

#define AS1(p) ((const __attribute__((address_space(1))) void*)(p))
#define AS3(p) ((__attribute__((address_space(3))) void*)(p))

// 16-lane (DPP row) rotate-reduce sum: VALU latency, no LDS round-trip.
template <int S>
__device__ __forceinline__ float ror16(float x) {
    return __builtin_bit_cast(float, __builtin_amdgcn_update_dpp(
        0, __builtin_bit_cast(int, x), 0x120 | S, 0xF, 0xF, true));
}
__device__ __forceinline__ float row_sum16(float x) {
    x += ror16<8>(x);
    x += ror16<4>(x);
    x += ror16<2>(x);
    x += ror16<1>(x);
    return x;
}

// ---------------------------------------------------------------------------
// All fp32 -> bf16 converts in one launch.
// Block ranges (float4 units, 256/blk): x 8192, wq 4096, wk 2048, wv 2048,
// wo 4096 -> 20480 blocks.
// ---------------------------------------------------------------------------
__global__ __launch_bounds__(256) void cvt_all(const float* __restrict__ x,
                                               const float* __restrict__ wq,
                                               const float* __restrict__ wk,
                                               const float* __restrict__ wv,
                                               const float* __restrict__ wo,
                                               __bf16* __restrict__ xb,
                                               __bf16* __restrict__ wb,
                                               __bf16* __restrict__ wob) {
    int bid = blockIdx.x;
    const float* src;
    __bf16* dst;
    int i4;
    if (bid < 8192)       { src = x;  dst = xb;                    i4 = bid * 256; }
    else if (bid < 12288) { src = wq; dst = wb;                    i4 = (bid - 8192) * 256; }
    else if (bid < 14336) { src = wk; dst = wb + (size_t)4194304;  i4 = (bid - 12288) * 256; }
    else if (bid < 16384) { src = wv; dst = wb + (size_t)6291456;  i4 = (bid - 14336) * 256; }
    else                  { src = wo; dst = wob;                   i4 = (bid - 16384) * 256; }
    i4 += threadIdx.x;
    float4 v = reinterpret_cast<const float4*>(src)[i4];
    bf16x4 o = {(__bf16)v.x, (__bf16)v.y, (__bf16)v.z, (__bf16)v.w};
    reinterpret_cast<bf16x4*>(dst)[i4] = o;
}

// ---------------------------------------------------------------------------
// RoPE cos/sin table: tab[s][0..63]=cos(ang_i), tab[s][64..127]=sin(ang_i).
// ---------------------------------------------------------------------------
__global__ __launch_bounds__(128) void build_rope(float* __restrict__ tab) {
    int s = blockIdx.x;
    int d = threadIdx.x;
    int i = d & 63;
    // inv_freq = 1e6^(-2i/128); log2(1e6) = 19.931568569324174
    float inv_freq = exp2f(-19.931568569324174f * (float)(2 * i) * (1.0f / 128.0f));
    float ang = (float)s * inv_freq;
    float sn, cs;
    sincosf(ang, &sn, &cs);
    tab[s * 128 + d] = (d < 64) ? cs : sn;
}

// ---------------------------------------------------------------------------
// bf16 MFMA NT GEMM: C[M,N] = A[M,K] * W[N,K]^T
// 128x128 tile, BK=64, 256 threads = 4 waves (2x2), global_load_lds width=16.
// XOR-swizzled LDS (R7): lane fetches global chunk (ch ^ row&7); fragment
// reads address chunk ((kk*4+quad) ^ (col&7)) -> 2-way banks = free.
// ---------------------------------------------------------------------------
template <typename CT>
__global__ __launch_bounds__(256) void gemm_bf16_nt(const __bf16* __restrict__ A,
                                                    const __bf16* __restrict__ W,
                                                    CT* __restrict__ C,
                                                    int M, int N, int K) {
    __shared__ __bf16 As[128 * 64];
    __shared__ __bf16 Bs[128 * 64];

    const int t    = threadIdx.x;
    const int w    = t >> 6;
    const int lane = t & 63;
    const int col  = lane & 15;
    const int quad = lane >> 4;
    const int wm   = w >> 1;
    const int wn   = w & 1;

    const int m0 = blockIdx.y * 128;
    const int n0 = blockIdx.x * 128;

    const int lrow8 = lane >> 3;                     // 0..7
    const int lch   = ((lane & 7) ^ lrow8) * 8;      // swizzled K-chunk

    const __bf16* agp = A + (size_t)(m0 + w * 32 + lrow8) * K + lch;
    const __bf16* wgp = W + (size_t)(n0 + w * 32 + lrow8) * K + lch;
    __bf16* alp = As + (w * 32) * 64;
    __bf16* blp = Bs + (w * 32) * 64;

    const int c7 = col & 7;

    f32x4 acc[4][4];
    #pragma unroll
    for (int m = 0; m < 4; m++)
        #pragma unroll
        for (int n = 0; n < 4; n++) acc[m][n] = (f32x4){0.f, 0.f, 0.f, 0.f};

    #pragma unroll 1
    for (int k0 = 0; k0 < K; k0 += 64) {
        #pragma unroll
        for (int j = 0; j < 4; j++) {
            __builtin_amdgcn_global_load_lds(AS1(agp + k0 + (size_t)(j * 8) * K),
                                             AS3(alp + j * 512), 16, 0, 0);
            __builtin_amdgcn_global_load_lds(AS1(wgp + k0 + (size_t)(j * 8) * K),
                                             AS3(blp + j * 512), 16, 0, 0);
        }
        __syncthreads();

        #pragma unroll
        for (int kk = 0; kk < 2; kk++) {
            bf16x8 af[4], bfr[4];
            #pragma unroll
            for (int m = 0; m < 4; m++)
                af[m] = *reinterpret_cast<const bf16x8*>(
                    &As[(wm * 64 + m * 16 + col) * 64 + ((kk * 4 + quad) ^ c7) * 8]);
            #pragma unroll
            for (int n = 0; n < 4; n++)
                bfr[n] = *reinterpret_cast<const bf16x8*>(
                    &Bs[(wn * 64 + n * 16 + col) * 64 + ((kk * 4 + quad) ^ c7) * 8]);

            #pragma unroll
            for (int m = 0; m < 4; m++)
                #pragma unroll
                for (int n = 0; n < 4; n++)
                    acc[m][n] = __builtin_amdgcn_mfma_f32_16x16x32_bf16(af[m], bfr[n], acc[m][n], 0, 0, 0);
        }
        __syncthreads();
    }

    #pragma unroll
    for (int m = 0; m < 4; m++) {
        #pragma unroll
        for (int r = 0; r < 4; r++) {
            size_t row = m0 + wm * 64 + m * 16 + quad * 4 + r;
            CT* cp = C + row * N + n0 + wn * 64 + col;
            #pragma unroll
            for (int n = 0; n < 4; n++) cp[n * 16] = (CT)acc[m][n][r];
        }
    }
}

// ---------------------------------------------------------------------------
// Fused per-head RMSNorm + RoPE for q AND k, cos/sin from precomputed table.
// Grid (BS, 24): head<16 -> q head, else k head-16 (base +2048).
// ---------------------------------------------------------------------------
__global__ __launch_bounds__(128) void norm_rope(__bf16* __restrict__ qkv,
                                                 const float* __restrict__ qw,
                                                 const float* __restrict__ kw,
                                                 const float* __restrict__ tab) {
    __shared__ float sred[2];
    __shared__ float nv[128];

    const int row  = blockIdx.x;
    const int s    = row & (S_ - 1);
    const int head = blockIdx.y;
    const int d    = threadIdx.x;

    const bool isq = head < H_;
    const float* w = isq ? qw : kw;
    __bf16* p = qkv + (size_t)row * NQKV
              + (isq ? (size_t)head * HD_ : (size_t)2048 + (size_t)(head - H_) * HD_);
    float x = (float)p[d];

    float ss = x * x;
    #pragma unroll
    for (int off = 32; off; off >>= 1) ss += __shfl_xor(ss, off);
    if ((threadIdx.x & 63) == 0) sred[threadIdx.x >> 6] = ss;
    __syncthreads();
    float mean = (sred[0] + sred[1]) * (1.0f / 128.0f);
    float rs = rsqrtf(mean + 1e-6f);

    float n = x * rs * w[d];
    nv[d] = n;
    __syncthreads();

    const int i = d & 63;
    float cs = tab[s * 128 + i];
    float sn = tab[s * 128 + 64 + i];

    float other = nv[d ^ 64];
    float r = (d < 64) ? (n * cs - other * sn)
                       : (other * sn + n * cs);
    p[d] = (__bf16)r;
}

// ---------------------------------------------------------------------------
// V transpose: vt[(b*HK+kvh)*128 + dim][s] = v[b*S+s][kvh*128+dim]
// ---------------------------------------------------------------------------
__global__ __launch_bounds__(256) void transpose_v(const __bf16* __restrict__ qkv,
                                                   __bf16* __restrict__ vt) {
    __shared__ __bf16 Ls[64][136];
    const int t  = threadIdx.x;
    const int bk = blockIdx.y;            // b*8 + kvh
    const int b  = bk >> 3;
    const int kvh = bk & 7;
    const int s0 = blockIdx.x * 64;

    #pragma unroll
    for (int i = 0; i < 4; i++) {
        int f = t + i * 256;
        int row = f >> 4;
        int d8 = (f & 15) * 8;
        bf16x8 v = *reinterpret_cast<const bf16x8*>(
            &qkv[(size_t)(b * S_ + s0 + row) * NQKV + 3072 + kvh * HD_ + d8]);
        *reinterpret_cast<bf16x8*>(&Ls[row][d8]) = v;
    }
    __syncthreads();

    #pragma unroll
    for (int i = 0; i < 4; i++) {
        int f = t + i * 256;
        int dim = f >> 3;
        int kc = f & 7;
        bf16x8 o;
        #pragma unroll
        for (int e = 0; e < 8; e++) o[e] = Ls[kc * 8 + e][dim];
        *reinterpret_cast<bf16x8*>(
            &vt[((size_t)bk * HD_ + dim) * S_ + s0 + kc * 8]) = o;
    }
}

// ---------------------------------------------------------------------------
// MFMA bf16 flash attention (causal, GQA rep=2), FIXED-MAX softmax.
// RMSNorm bounds |score| <= sqrt(128) ~= 11.32, so p = exp2(fma(s,C0,CM))
// with M=12 never overflows: no running max, no alpha rescale, no per-tile
// DPP reductions. l accumulated per-lane, one DPP row-sum at epilogue.
// Grid: (B*H, S/64) — y is the q-tile, biggest tiles dispatched FIRST.
// LDS: union{ Qs | Ks } + Vt + Ps = 45056 B -> 3 blocks/CU.
// ---------------------------------------------------------------------------
__global__ __launch_bounds__(256) void attn_mfma(const __bf16* __restrict__ qkv,
                                                 const __bf16* __restrict__ vt,
                                                 __bf16* __restrict__ ao) {
    __shared__ __align__(16) char smem[17408];
    __bf16 (*Qs)[136] = reinterpret_cast<__bf16(*)[136]>(smem);
    __bf16 (*Ks)[136] = reinterpret_cast<__bf16(*)[136]>(smem);
    __shared__ __bf16 Vt[128][72];
    __shared__ __bf16 Ps[4][16][72];

    const int t    = threadIdx.x;
    const int w    = t >> 6;
    const int lane = t & 63;
    const int col  = lane & 15;
    const int quad = lane >> 4;

    const int bh  = blockIdx.x;
    const int b   = bh >> 4;
    const int h   = bh & 15;
    const int kvh = h >> 1;
    const int qb  = gridDim.y - 1 - blockIdx.y;   // big q-tiles first
    const int r0  = qb * 64;

    const float C0 = SCALE * 1.44269504f;     // score scale -> log2 domain
    const float CM = -12.0f * 1.44269504f;    // fixed-max offset

    const __bf16* vbase = vt + ((size_t)(b * HK_ + kvh) * HD_) * S_;

    // per-thread staging addresses (fixed shape, advance per tile)
    const __bf16* kp[4];
    __bf16*       kw_[4];
    const __bf16* vp[4];
    __bf16*       vw_[4];
    #pragma unroll
    for (int i = 0; i < 4; i++) {
        int f = t + i * 256;
        int row = f >> 4, d8 = (f & 15) * 8;
        kp[i]  = qkv + (size_t)(b * S_ + row) * NQKV + 2048 + kvh * HD_ + d8;
        kw_[i] = &Ks[row][d8];
        int dim = f >> 3, kc = f & 7;
        vp[i]  = vbase + (size_t)dim * S_ + kc * 8;
        vw_[i] = &Vt[dim][kc * 8];
    }

    // ---- prefetch K/V tile 0 into registers ----
    bf16x8 kreg[4], vreg[4];
    #pragma unroll
    for (int i = 0; i < 4; i++) {
        kreg[i] = *reinterpret_cast<const bf16x8*>(kp[i]);  kp[i] += (size_t)64 * NQKV;
        vreg[i] = *reinterpret_cast<const bf16x8*>(vp[i]);  vp[i] += 64;
    }

    // ---- stage Q tile (64 rows x 128) into Qs (overlays Ks) ----
    #pragma unroll
    for (int i = 0; i < 4; i++) {
        int f   = t + i * 256;
        int row = f >> 4;
        int d8  = (f & 15) * 8;
        bf16x8 v = *reinterpret_cast<const bf16x8*>(
            &qkv[(size_t)(b * S_ + r0 + row) * NQKV + h * HD_ + d8]);
        *reinterpret_cast<bf16x8*>(&Qs[row][d8]) = v;
    }
    __syncthreads();

    bf16x8 qf[4];
    {
        const int m = w * 16 + col;
        #pragma unroll
        for (int k = 0; k < 4; k++)
            qf[k] = *reinterpret_cast<const bf16x8*>(&Qs[m][k * 32 + quad * 8]);
    }

    f32x4 o_acc[8];
    #pragma unroll
    for (int i = 0; i < 8; i++) o_acc[i] = (f32x4){0.f, 0.f, 0.f, 0.f};
    float l_lane[4] = {0.f, 0.f, 0.f, 0.f};

    const int ntiles = qb + 1;
    for (int ti = 0; ti < ntiles; ti++) {
        __syncthreads();   // prior-tile LDS reads (and iter-0 qf grab) done

        // ---- write prefetched K/V regs into LDS ----
        #pragma unroll
        for (int i = 0; i < 4; i++) {
            *reinterpret_cast<bf16x8*>(kw_[i]) = kreg[i];
            *reinterpret_cast<bf16x8*>(vw_[i]) = vreg[i];
        }
        // ---- issue next tile's global loads (overlap with compute) ----
        if (ti + 1 < ntiles) {
            #pragma unroll
            for (int i = 0; i < 4; i++) {
                kreg[i] = *reinterpret_cast<const bf16x8*>(kp[i]);  kp[i] += (size_t)64 * NQKV;
                vreg[i] = *reinterpret_cast<const bf16x8*>(vp[i]);  vp[i] += 64;
            }
        }
        __syncthreads();

        // ---- S = Q K^T (16 q-rows x 64 keys) ----
        f32x4 s[4];
        #pragma unroll
        for (int n = 0; n < 4; n++) {
            f32x4 acc = (f32x4){0.f, 0.f, 0.f, 0.f};
            #pragma unroll
            for (int k = 0; k < 4; k++) {
                bf16x8 bf = *reinterpret_cast<const bf16x8*>(
                    &Ks[n * 16 + col][k * 32 + quad * 8]);
                acc = __builtin_amdgcn_mfma_f32_16x16x32_bf16(qf[k], bf, acc, 0, 0, 0);
            }
            s[n] = acc;
        }

        // ---- fixed-max softmax: p = exp2(s*C0 + CM), no reductions ----
        const bool diag = (ti == qb);
        #pragma unroll
        for (int r = 0; r < 4; r++) {
            float p0 = exp2f(fmaf(s[0][r], C0, CM));
            float p1 = exp2f(fmaf(s[1][r], C0, CM));
            float p2 = exp2f(fmaf(s[2][r], C0, CM));
            float p3 = exp2f(fmaf(s[3][r], C0, CM));
            if (diag) {
                int qloc = w * 16 + quad * 4 + r;
                if (0 * 16 + col > qloc) p0 = 0.f;
                if (1 * 16 + col > qloc) p1 = 0.f;
                if (2 * 16 + col > qloc) p2 = 0.f;
                if (3 * 16 + col > qloc) p3 = 0.f;
            }
            l_lane[r] += p0 + p1 + p2 + p3;
            Ps[w][quad * 4 + r][0 * 16 + col] = (__bf16)p0;
            Ps[w][quad * 4 + r][1 * 16 + col] = (__bf16)p1;
            Ps[w][quad * 4 + r][2 * 16 + col] = (__bf16)p2;
            Ps[w][quad * 4 + r][3 * 16 + col] = (__bf16)p3;
        }

        // ---- PV (same-wave RAW on Ps: no barrier needed) ----
        bf16x8 pf[2];
        #pragma unroll
        for (int ks = 0; ks < 2; ks++)
            pf[ks] = *reinterpret_cast<const bf16x8*>(&Ps[w][col][ks * 32 + quad * 8]);
        #pragma unroll
        for (int n = 0; n < 8; n++) {
            #pragma unroll
            for (int ks = 0; ks < 2; ks++) {
                bf16x8 vf = *reinterpret_cast<const bf16x8*>(
                    &Vt[n * 16 + col][ks * 32 + quad * 8]);
                o_acc[n] = __builtin_amdgcn_mfma_f32_16x16x32_bf16(pf[ks], vf, o_acc[n], 0, 0, 0);
            }
        }
    }

    // ---- epilogue: one row-sum per r, then normalize ----
    #pragma unroll
    for (int r = 0; r < 4; r++) {
        float l = row_sum16(l_lane[r]);
        float inv = 1.0f / l;
        int qrow = r0 + w * 16 + quad * 4 + r;
        __bf16* op = ao + (size_t)(b * S_ + qrow) * (H_ * HD_) + h * HD_ + col;
        #pragma unroll
        for (int n = 0; n < 8; n++)
            op[n * 16] = (__bf16)(o_acc[n][r] * inv);
    }
}

// ---------------------------------------------------------------------------
extern "C" void kernel_launch(void* const* d_in, const int* in_sizes, int n_in,
                              void* d_out, int out_size, void* d_ws, size_t ws_size,
                              hipStream_t stream) {
    const float* x  = (const float*)d_in[0];
    const float* wq = (const float*)d_in[1];
    const float* wk = (const float*)d_in[2];
    const float* wv = (const float*)d_in[3];
    const float* wo = (const float*)d_in[4];
    const float* qw = (const float*)d_in[5];
    const float* kw = (const float*)d_in[6];
    float* out = (float*)d_out;

    // workspace (bf16 elements), total 50.33M elems = 100.66 MB
    __bf16* ws  = (__bf16*)d_ws;
    __bf16* xb  = ws;                               // [4096][2048]  8.4M
    __bf16* wb  = xb  + (size_t)8388608;            // [4096][2048]  8.4M (wq|wk|wv)
    __bf16* wob = wb  + (size_t)8388608;            // [2048][2048]  4.2M
    __bf16* qkv = wob + (size_t)4194304;            // [4096][4096] 16.8M
    __bf16* ao  = qkv + (size_t)16777216;           // [4096][2048]  8.4M
    __bf16* vtg = ao  + (size_t)8388608;            // [16][128][2048] 4.2M
    // rope table lives in the ao region (dead until attn writes it, and
    // norm_rope finishes reading the table before attn runs — stream order)
    float* rtab = (float*)ao;                       // [2048][128] fp32 = 1 MB

    cvt_all<<<20480, 256, 0, stream>>>(x, wq, wk, wv, wo, xb, wb, wob);
    build_rope<<<S_, 128, 0, stream>>>(rtab);

    // fused QKV projection
    gemm_bf16_nt<__bf16><<<dim3(NQKV / 128, BS_ / 128), 256, 0, stream>>>(
        xb, wb, qkv, BS_, NQKV, D_);

    // RMSNorm + RoPE on q (heads 0..15) and k (heads 16..23), one launch
    norm_rope<<<dim3(BS_, H_ + HK_), 128, 0, stream>>>(qkv, qw, kw, rtab);

    // global V^T
    transpose_v<<<dim3(S_ / 64, B_ * HK_), 256, 0, stream>>>(qkv, vtg);

    // causal GQA attention (x = bh, y = q-tile big-first)
    attn_mfma<<<dim3(B_ * H_, S_ / 64), 256, 0, stream>>>(qkv, vtg, ao);

    // output projection
    gemm_bf16_nt<float><<<dim3(D_ / 128, BS_ / 128), 256, 0, stream>>>(
        ao, wob, out, BS_, D_, H_ * HD_);
}

// Round 10
// 346.728 us; speedup vs baseline: 1.8818x; 1.0588x over previous
//
#include <hip/hip_runtime.h>
#include <hip/hip_bf16.h>
#include <math.h>

// Problem constants (Qwen3-style attention block)
#define B_   2
#define S_   2048
#define D_   2048
#define H_   16
#define HK_  8
#define HD_  128
#define BS_  (B_ * S_)          // 4096 rows
#define NQKV 4096               // combined q(2048) + k(1024) + v(1024) cols
#define SCALE 0.08838834764831845f  // 1/sqrt(128)

typedef __bf16 bf16x8 __attribute__((ext_vector_type(8)));
typedef __bf16 bf16x4 __attribute__((ext_vector_type(4)));
typedef float  f32x4  __attribute__((ext_vector_type(4)));

#define AS1(p) ((const __attribute__((address_space(1))) void*)(p))
#define AS3(p) ((__attribute__((address_space(3))) void*)(p))

// 16-lane (DPP row) rotate-reduce sum: VALU latency, no LDS round-trip.
template <int S>
__device__ __forceinline__ float ror16(float x) {
    return __builtin_bit_cast(float, __builtin_amdgcn_update_dpp(
        0, __builtin_bit_cast(int, x), 0x120 | S, 0xF, 0xF, true));
}
__device__ __forceinline__ float row_sum16(float x) {
    x += ror16<8>(x);
    x += ror16<4>(x);
    x += ror16<2>(x);
    x += ror16<1>(x);
    return x;
}

// ---------------------------------------------------------------------------
// All fp32 -> bf16 converts in one launch.
// Block ranges (float4 units, 256/blk): x 8192, wq 4096, wk 2048, wv 2048,
// wo 4096 -> 20480 blocks.
// ---------------------------------------------------------------------------
__global__ __launch_bounds__(256) void cvt_all(const float* __restrict__ x,
                                               const float* __restrict__ wq,
                                               const float* __restrict__ wk,
                                               const float* __restrict__ wv,
                                               const float* __restrict__ wo,
                                               __bf16* __restrict__ xb,
                                               __bf16* __restrict__ wb,
                                               __bf16* __restrict__ wob) {
    int bid = blockIdx.x;
    const float* src;
    __bf16* dst;
    int i4;
    if (bid < 8192)       { src = x;  dst = xb;                    i4 = bid * 256; }
    else if (bid < 12288) { src = wq; dst = wb;                    i4 = (bid - 8192) * 256; }
    else if (bid < 14336) { src = wk; dst = wb + (size_t)4194304;  i4 = (bid - 12288) * 256; }
    else if (bid < 16384) { src = wv; dst = wb + (size_t)6291456;  i4 = (bid - 14336) * 256; }
    else                  { src = wo; dst = wob;                   i4 = (bid - 16384) * 256; }
    i4 += threadIdx.x;
    float4 v = reinterpret_cast<const float4*>(src)[i4];
    bf16x4 o = {(__bf16)v.x, (__bf16)v.y, (__bf16)v.z, (__bf16)v.w};
    reinterpret_cast<bf16x4*>(dst)[i4] = o;
}

// ---------------------------------------------------------------------------
// RoPE cos/sin table: tab[s][0..63]=cos(ang_i), tab[s][64..127]=sin(ang_i).
// ---------------------------------------------------------------------------
__global__ __launch_bounds__(128) void build_rope(float* __restrict__ tab) {
    int s = blockIdx.x;
    int d = threadIdx.x;
    int i = d & 63;
    float inv_freq = exp2f(-19.931568569324174f * (float)(2 * i) * (1.0f / 128.0f));
    float ang = (float)s * inv_freq;
    float sn, cs;
    sincosf(ang, &sn, &cs);
    tab[s * 128 + d] = (d < 64) ? cs : sn;
}

// ---------------------------------------------------------------------------
// bf16 MFMA NT GEMM: C[M,N] = A[M,K] * W[N,K]^T
// 128x128 tile, BK=64, 256 threads = 4 waves (2x2), global_load_lds width=16.
// XOR-swizzled LDS (R7): conflict-free (verified R8: SQ_LDS_BANK_CONFLICT=0).
// ---------------------------------------------------------------------------
template <typename CT>
__global__ __launch_bounds__(256) void gemm_bf16_nt(const __bf16* __restrict__ A,
                                                    const __bf16* __restrict__ W,
                                                    CT* __restrict__ C,
                                                    int M, int N, int K) {
    __shared__ __bf16 As[128 * 64];
    __shared__ __bf16 Bs[128 * 64];

    const int t    = threadIdx.x;
    const int w    = t >> 6;
    const int lane = t & 63;
    const int col  = lane & 15;
    const int quad = lane >> 4;
    const int wm   = w >> 1;
    const int wn   = w & 1;

    const int m0 = blockIdx.y * 128;
    const int n0 = blockIdx.x * 128;

    const int lrow8 = lane >> 3;                     // 0..7
    const int lch   = ((lane & 7) ^ lrow8) * 8;      // swizzled K-chunk

    const __bf16* agp = A + (size_t)(m0 + w * 32 + lrow8) * K + lch;
    const __bf16* wgp = W + (size_t)(n0 + w * 32 + lrow8) * K + lch;
    __bf16* alp = As + (w * 32) * 64;
    __bf16* blp = Bs + (w * 32) * 64;

    const int c7 = col & 7;

    f32x4 acc[4][4];
    #pragma unroll
    for (int m = 0; m < 4; m++)
        #pragma unroll
        for (int n = 0; n < 4; n++) acc[m][n] = (f32x4){0.f, 0.f, 0.f, 0.f};

    #pragma unroll 1
    for (int k0 = 0; k0 < K; k0 += 64) {
        #pragma unroll
        for (int j = 0; j < 4; j++) {
            __builtin_amdgcn_global_load_lds(AS1(agp + k0 + (size_t)(j * 8) * K),
                                             AS3(alp + j * 512), 16, 0, 0);
            __builtin_amdgcn_global_load_lds(AS1(wgp + k0 + (size_t)(j * 8) * K),
                                             AS3(blp + j * 512), 16, 0, 0);
        }
        __syncthreads();

        #pragma unroll
        for (int kk = 0; kk < 2; kk++) {
            bf16x8 af[4], bfr[4];
            #pragma unroll
            for (int m = 0; m < 4; m++)
                af[m] = *reinterpret_cast<const bf16x8*>(
                    &As[(wm * 64 + m * 16 + col) * 64 + ((kk * 4 + quad) ^ c7) * 8]);
            #pragma unroll
            for (int n = 0; n < 4; n++)
                bfr[n] = *reinterpret_cast<const bf16x8*>(
                    &Bs[(wn * 64 + n * 16 + col) * 64 + ((kk * 4 + quad) ^ c7) * 8]);

            #pragma unroll
            for (int m = 0; m < 4; m++)
                #pragma unroll
                for (int n = 0; n < 4; n++)
                    acc[m][n] = __builtin_amdgcn_mfma_f32_16x16x32_bf16(af[m], bfr[n], acc[m][n], 0, 0, 0);
        }
        __syncthreads();
    }

    #pragma unroll
    for (int m = 0; m < 4; m++) {
        #pragma unroll
        for (int r = 0; r < 4; r++) {
            size_t row = m0 + wm * 64 + m * 16 + quad * 4 + r;
            CT* cp = C + row * N + n0 + wn * 64 + col;
            #pragma unroll
            for (int n = 0; n < 4; n++) cp[n * 16] = (CT)acc[m][n][r];
        }
    }
}

// ---------------------------------------------------------------------------
// bf16 MFMA NT GEMM, 128(M)x64(N) tile: for narrow-N GEMMs where the 128x128
// grid would be too small for CU overlap (out-proj: N=2048 -> 1024 blocks).
// Waves 2x2 over (64 M x 32 N). LDS 24 KB.
// ---------------------------------------------------------------------------
template <typename CT>
__global__ __launch_bounds__(256) void gemm_bf16_nt_n64(const __bf16* __restrict__ A,
                                                        const __bf16* __restrict__ W,
                                                        CT* __restrict__ C,
                                                        int M, int N, int K) {
    __shared__ __bf16 As[128 * 64];
    __shared__ __bf16 Bs[64 * 64];

    const int t    = threadIdx.x;
    const int w    = t >> 6;
    const int lane = t & 63;
    const int col  = lane & 15;
    const int quad = lane >> 4;
    const int wm   = w >> 1;      // 0..1 -> M half (64 rows)
    const int wn   = w & 1;       // 0..1 -> N half (32 cols)

    const int m0 = blockIdx.x * 128;
    const int n0 = blockIdx.y * 64;

    const int lrow8 = lane >> 3;
    const int lch   = ((lane & 7) ^ lrow8) * 8;

    const __bf16* agp = A + (size_t)(m0 + w * 32 + lrow8) * K + lch;
    const __bf16* wgp = W + (size_t)(n0 + w * 16 + lrow8) * K + lch;
    __bf16* alp = As + (w * 32) * 64;
    __bf16* blp = Bs + (w * 16) * 64;

    const int c7 = col & 7;

    f32x4 acc[4][2];
    #pragma unroll
    for (int m = 0; m < 4; m++)
        #pragma unroll
        for (int n = 0; n < 2; n++) acc[m][n] = (f32x4){0.f, 0.f, 0.f, 0.f};

    #pragma unroll 1
    for (int k0 = 0; k0 < K; k0 += 64) {
        #pragma unroll
        for (int j = 0; j < 4; j++)
            __builtin_amdgcn_global_load_lds(AS1(agp + k0 + (size_t)(j * 8) * K),
                                             AS3(alp + j * 512), 16, 0, 0);
        #pragma unroll
        for (int j = 0; j < 2; j++)
            __builtin_amdgcn_global_load_lds(AS1(wgp + k0 + (size_t)(j * 8) * K),
                                             AS3(blp + j * 512), 16, 0, 0);
        __syncthreads();

        #pragma unroll
        for (int kk = 0; kk < 2; kk++) {
            bf16x8 af[4], bfr[2];
            #pragma unroll
            for (int m = 0; m < 4; m++)
                af[m] = *reinterpret_cast<const bf16x8*>(
                    &As[(wm * 64 + m * 16 + col) * 64 + ((kk * 4 + quad) ^ c7) * 8]);
            #pragma unroll
            for (int n = 0; n < 2; n++)
                bfr[n] = *reinterpret_cast<const bf16x8*>(
                    &Bs[(wn * 32 + n * 16 + col) * 64 + ((kk * 4 + quad) ^ c7) * 8]);

            #pragma unroll
            for (int m = 0; m < 4; m++)
                #pragma unroll
                for (int n = 0; n < 2; n++)
                    acc[m][n] = __builtin_amdgcn_mfma_f32_16x16x32_bf16(af[m], bfr[n], acc[m][n], 0, 0, 0);
        }
        __syncthreads();
    }

    #pragma unroll
    for (int m = 0; m < 4; m++) {
        #pragma unroll
        for (int r = 0; r < 4; r++) {
            size_t row = m0 + wm * 64 + m * 16 + quad * 4 + r;
            CT* cp = C + row * N + n0 + wn * 32 + col;
            #pragma unroll
            for (int n = 0; n < 2; n++) cp[n * 16] = (CT)acc[m][n][r];
        }
    }
}

// ---------------------------------------------------------------------------
// Fused per-head RMSNorm + RoPE, vectorized: one head per 16-lane DPP row.
// 256 threads = 16 heads/block; lane-in-row l handles elems l*8..l*8+7.
// Sum-of-squares via row_sum16 (DPP); RoPE pair (d ^ 64) via shfl_xor(.,8).
// Grid: BS*24/16 = 6144 blocks. Head h (0..23) lives at cols h*128 (q then k).
// ---------------------------------------------------------------------------
__global__ __launch_bounds__(256) void norm_rope(__bf16* __restrict__ qkv,
                                                 const float* __restrict__ qw,
                                                 const float* __restrict__ kw,
                                                 const float* __restrict__ tab) {
    const int g    = blockIdx.x * 16 + (threadIdx.x >> 4);  // head-instance
    const int l    = threadIdx.x & 15;
    const int row  = g / 24;
    const int head = g - row * 24;
    const int s    = row & (S_ - 1);

    const float* w = (head < H_) ? qw : kw;
    __bf16* p = qkv + (size_t)row * NQKV + head * HD_ + l * 8;

    bf16x8 xv = *reinterpret_cast<const bf16x8*>(p);
    float xf[8];
    float ss = 0.f;
    #pragma unroll
    for (int j = 0; j < 8; j++) { xf[j] = (float)xv[j]; ss = fmaf(xf[j], xf[j], ss); }
    ss = row_sum16(ss);
    float rs = rsqrtf(ss * (1.0f / 128.0f) + 1e-6f);

    // normed value (fp32)
    float nf[8];
    const float4 w0 = *reinterpret_cast<const float4*>(&w[l * 8]);
    const float4 w1 = *reinterpret_cast<const float4*>(&w[l * 8 + 4]);
    nf[0] = xf[0] * rs * w0.x; nf[1] = xf[1] * rs * w0.y;
    nf[2] = xf[2] * rs * w0.z; nf[3] = xf[3] * rs * w0.w;
    nf[4] = xf[4] * rs * w1.x; nf[5] = xf[5] * rs * w1.y;
    nf[6] = xf[6] * rs * w1.z; nf[7] = xf[7] * rs * w1.w;

    // RoPE pair values from the other half (lane l^8, same j)
    float of[8];
    #pragma unroll
    for (int j = 0; j < 8; j++) of[j] = __shfl_xor(nf[j], 8);

    // cos/sin for freq index i = (l&7)*8 + j
    const int ib = (l & 7) * 8;
    const float4 c0 = *reinterpret_cast<const float4*>(&tab[s * 128 + ib]);
    const float4 c1 = *reinterpret_cast<const float4*>(&tab[s * 128 + ib + 4]);
    const float4 s0 = *reinterpret_cast<const float4*>(&tab[s * 128 + 64 + ib]);
    const float4 s1 = *reinterpret_cast<const float4*>(&tab[s * 128 + 64 + ib + 4]);
    float cs[8] = {c0.x, c0.y, c0.z, c0.w, c1.x, c1.y, c1.z, c1.w};
    float sn[8] = {s0.x, s0.y, s0.z, s0.w, s1.x, s1.y, s1.z, s1.w};

    bf16x8 out;
    if (l < 8) {
        #pragma unroll
        for (int j = 0; j < 8; j++) out[j] = (__bf16)(nf[j] * cs[j] - of[j] * sn[j]);
    } else {
        #pragma unroll
        for (int j = 0; j < 8; j++) out[j] = (__bf16)(of[j] * sn[j] + nf[j] * cs[j]);
    }
    *reinterpret_cast<bf16x8*>(p) = out;
}

// ---------------------------------------------------------------------------
// V transpose: vt[(b*HK+kvh)*128 + dim][s] = v[b*S+s][kvh*128+dim]
// ---------------------------------------------------------------------------
__global__ __launch_bounds__(256) void transpose_v(const __bf16* __restrict__ qkv,
                                                   __bf16* __restrict__ vt) {
    __shared__ __bf16 Ls[64][136];
    const int t  = threadIdx.x;
    const int bk = blockIdx.y;            // b*8 + kvh
    const int b  = bk >> 3;
    const int kvh = bk & 7;
    const int s0 = blockIdx.x * 64;

    #pragma unroll
    for (int i = 0; i < 4; i++) {
        int f = t + i * 256;
        int row = f >> 4;
        int d8 = (f & 15) * 8;
        bf16x8 v = *reinterpret_cast<const bf16x8*>(
            &qkv[(size_t)(b * S_ + s0 + row) * NQKV + 3072 + kvh * HD_ + d8]);
        *reinterpret_cast<bf16x8*>(&Ls[row][d8]) = v;
    }
    __syncthreads();

    #pragma unroll
    for (int i = 0; i < 4; i++) {
        int f = t + i * 256;
        int dim = f >> 3;
        int kc = f & 7;
        bf16x8 o;
        #pragma unroll
        for (int e = 0; e < 8; e++) o[e] = Ls[kc * 8 + e][dim];
        *reinterpret_cast<bf16x8*>(
            &vt[((size_t)bk * HD_ + dim) * S_ + s0 + kc * 8]) = o;
    }
}

// ---------------------------------------------------------------------------
// MFMA bf16 flash attention (causal, GQA rep=2), fixed-max softmax (R8).
// Grid: (B*H, S/64) — y is the q-tile, biggest tiles dispatched FIRST.
// LDS: union{ Qs | Ks } + Vt + Ps = 45056 B -> 3 blocks/CU.
// ---------------------------------------------------------------------------
__global__ __launch_bounds__(256) void attn_mfma(const __bf16* __restrict__ qkv,
                                                 const __bf16* __restrict__ vt,
                                                 __bf16* __restrict__ ao) {
    __shared__ __align__(16) char smem[17408];
    __bf16 (*Qs)[136] = reinterpret_cast<__bf16(*)[136]>(smem);
    __bf16 (*Ks)[136] = reinterpret_cast<__bf16(*)[136]>(smem);
    __shared__ __bf16 Vt[128][72];
    __shared__ __bf16 Ps[4][16][72];

    const int t    = threadIdx.x;
    const int w    = t >> 6;
    const int lane = t & 63;
    const int col  = lane & 15;
    const int quad = lane >> 4;

    const int bh  = blockIdx.x;
    const int b   = bh >> 4;
    const int h   = bh & 15;
    const int kvh = h >> 1;
    const int qb  = gridDim.y - 1 - blockIdx.y;   // big q-tiles first
    const int r0  = qb * 64;

    const float C0 = SCALE * 1.44269504f;
    const float CM = -12.0f * 1.44269504f;

    const __bf16* vbase = vt + ((size_t)(b * HK_ + kvh) * HD_) * S_;

    const __bf16* kp[4];
    __bf16*       kw_[4];
    const __bf16* vp[4];
    __bf16*       vw_[4];
    #pragma unroll
    for (int i = 0; i < 4; i++) {
        int f = t + i * 256;
        int row = f >> 4, d8 = (f & 15) * 8;
        kp[i]  = qkv + (size_t)(b * S_ + row) * NQKV + 2048 + kvh * HD_ + d8;
        kw_[i] = &Ks[row][d8];
        int dim = f >> 3, kc = f & 7;
        vp[i]  = vbase + (size_t)dim * S_ + kc * 8;
        vw_[i] = &Vt[dim][kc * 8];
    }

    bf16x8 kreg[4], vreg[4];
    #pragma unroll
    for (int i = 0; i < 4; i++) {
        kreg[i] = *reinterpret_cast<const bf16x8*>(kp[i]);  kp[i] += (size_t)64 * NQKV;
        vreg[i] = *reinterpret_cast<const bf16x8*>(vp[i]);  vp[i] += 64;
    }

    #pragma unroll
    for (int i = 0; i < 4; i++) {
        int f   = t + i * 256;
        int row = f >> 4;
        int d8  = (f & 15) * 8;
        bf16x8 v = *reinterpret_cast<const bf16x8*>(
            &qkv[(size_t)(b * S_ + r0 + row) * NQKV + h * HD_ + d8]);
        *reinterpret_cast<bf16x8*>(&Qs[row][d8]) = v;
    }
    __syncthreads();

    bf16x8 qf[4];
    {
        const int m = w * 16 + col;
        #pragma unroll
        for (int k = 0; k < 4; k++)
            qf[k] = *reinterpret_cast<const bf16x8*>(&Qs[m][k * 32 + quad * 8]);
    }

    f32x4 o_acc[8];
    #pragma unroll
    for (int i = 0; i < 8; i++) o_acc[i] = (f32x4){0.f, 0.f, 0.f, 0.f};
    float l_lane[4] = {0.f, 0.f, 0.f, 0.f};

    const int ntiles = qb + 1;
    for (int ti = 0; ti < ntiles; ti++) {
        __syncthreads();

        #pragma unroll
        for (int i = 0; i < 4; i++) {
            *reinterpret_cast<bf16x8*>(kw_[i]) = kreg[i];
            *reinterpret_cast<bf16x8*>(vw_[i]) = vreg[i];
        }
        if (ti + 1 < ntiles) {
            #pragma unroll
            for (int i = 0; i < 4; i++) {
                kreg[i] = *reinterpret_cast<const bf16x8*>(kp[i]);  kp[i] += (size_t)64 * NQKV;
                vreg[i] = *reinterpret_cast<const bf16x8*>(vp[i]);  vp[i] += 64;
            }
        }
        __syncthreads();

        f32x4 s[4];
        #pragma unroll
        for (int n = 0; n < 4; n++) {
            f32x4 acc = (f32x4){0.f, 0.f, 0.f, 0.f};
            #pragma unroll
            for (int k = 0; k < 4; k++) {
                bf16x8 bf = *reinterpret_cast<const bf16x8*>(
                    &Ks[n * 16 + col][k * 32 + quad * 8]);
                acc = __builtin_amdgcn_mfma_f32_16x16x32_bf16(qf[k], bf, acc, 0, 0, 0);
            }
            s[n] = acc;
        }

        const bool diag = (ti == qb);
        #pragma unroll
        for (int r = 0; r < 4; r++) {
            float p0 = exp2f(fmaf(s[0][r], C0, CM));
            float p1 = exp2f(fmaf(s[1][r], C0, CM));
            float p2 = exp2f(fmaf(s[2][r], C0, CM));
            float p3 = exp2f(fmaf(s[3][r], C0, CM));
            if (diag) {
                int qloc = w * 16 + quad * 4 + r;
                if (0 * 16 + col > qloc) p0 = 0.f;
                if (1 * 16 + col > qloc) p1 = 0.f;
                if (2 * 16 + col > qloc) p2 = 0.f;
                if (3 * 16 + col > qloc) p3 = 0.f;
            }
            l_lane[r] += p0 + p1 + p2 + p3;
            Ps[w][quad * 4 + r][0 * 16 + col] = (__bf16)p0;
            Ps[w][quad * 4 + r][1 * 16 + col] = (__bf16)p1;
            Ps[w][quad * 4 + r][2 * 16 + col] = (__bf16)p2;
            Ps[w][quad * 4 + r][3 * 16 + col] = (__bf16)p3;
        }

        bf16x8 pf[2];
        #pragma unroll
        for (int ks = 0; ks < 2; ks++)
            pf[ks] = *reinterpret_cast<const bf16x8*>(&Ps[w][col][ks * 32 + quad * 8]);
        #pragma unroll
        for (int n = 0; n < 8; n++) {
            #pragma unroll
            for (int ks = 0; ks < 2; ks++) {
                bf16x8 vf = *reinterpret_cast<const bf16x8*>(
                    &Vt[n * 16 + col][ks * 32 + quad * 8]);
                o_acc[n] = __builtin_amdgcn_mfma_f32_16x16x32_bf16(pf[ks], vf, o_acc[n], 0, 0, 0);
            }
        }
    }

    #pragma unroll
    for (int r = 0; r < 4; r++) {
        float l = row_sum16(l_lane[r]);
        float inv = 1.0f / l;
        int qrow = r0 + w * 16 + quad * 4 + r;
        __bf16* op = ao + (size_t)(b * S_ + qrow) * (H_ * HD_) + h * HD_ + col;
        #pragma unroll
        for (int n = 0; n < 8; n++)
            op[n * 16] = (__bf16)(o_acc[n][r] * inv);
    }
}

// ---------------------------------------------------------------------------
extern "C" void kernel_launch(void* const* d_in, const int* in_sizes, int n_in,
                              void* d_out, int out_size, void* d_ws, size_t ws_size,
                              hipStream_t stream) {
    const float* x  = (const float*)d_in[0];
    const float* wq = (const float*)d_in[1];
    const float* wk = (const float*)d_in[2];
    const float* wv = (const float*)d_in[3];
    const float* wo = (const float*)d_in[4];
    const float* qw = (const float*)d_in[5];
    const float* kw = (const float*)d_in[6];
    float* out = (float*)d_out;

    // workspace (bf16 elements), total 50.33M elems = 100.66 MB
    __bf16* ws  = (__bf16*)d_ws;
    __bf16* xb  = ws;                               // [4096][2048]  8.4M
    __bf16* wb  = xb  + (size_t)8388608;            // [4096][2048]  8.4M (wq|wk|wv)
    __bf16* wob = wb  + (size_t)8388608;            // [2048][2048]  4.2M
    __bf16* qkv = wob + (size_t)4194304;            // [4096][4096] 16.8M
    __bf16* ao  = qkv + (size_t)16777216;           // [4096][2048]  8.4M
    __bf16* vtg = ao  + (size_t)8388608;            // [16][128][2048] 4.2M
    // rope table lives in the ao region (dead until attn writes it; norm_rope
    // finishes reading the table before attn runs — stream order)
    float* rtab = (float*)ao;                       // [2048][128] fp32 = 1 MB

    cvt_all<<<20480, 256, 0, stream>>>(x, wq, wk, wv, wo, xb, wb, wob);
    build_rope<<<S_, 128, 0, stream>>>(rtab);

    // fused QKV projection
    gemm_bf16_nt<__bf16><<<dim3(NQKV / 128, BS_ / 128), 256, 0, stream>>>(
        xb, wb, qkv, BS_, NQKV, D_);

    // RMSNorm + RoPE on q+k (24 heads x 4096 rows, 16 heads/block)
    norm_rope<<<(BS_ * 24) / 16, 256, 0, stream>>>(qkv, qw, kw, rtab);

    // global V^T
    transpose_v<<<dim3(S_ / 64, B_ * HK_), 256, 0, stream>>>(qkv, vtg);

    // causal GQA attention (x = bh, y = q-tile big-first)
    attn_mfma<<<dim3(B_ * H_, S_ / 64), 256, 0, stream>>>(qkv, vtg, ao);

    // output projection: 128x64 tiles -> 1024 blocks (CU overlap)
    gemm_bf16_nt_n64<float><<<dim3(BS_ / 128, D_ / 64), 256, 0, stream>>>(
        ao, wob, out, BS_, D_, H_ * HD_);
}